// Round 3
// baseline (203.089 us; speedup 1.0000x reference)
//
#include <hip/hip_runtime.h>
#include <hip/hip_bf16.h>

// N3 aggregation: C=64, E=32, H=W=128, K=7, PS=7 (PR=3), WS=13 (WR=6), O=169
#define HW 16384

using u16 = unsigned short;
using u32 = unsigned int;

__device__ __forceinline__ float bf2f(u16 u) {
    u32 x = ((u32)u) << 16;
    return __uint_as_float(x);
}
__device__ __forceinline__ u16 f2bf(float f) {  // round-to-nearest-even
    u32 b = __float_as_uint(f);
    u32 r = (b + 0x7FFFu + ((b >> 16) & 1u)) >> 16;
    return (u16)r;
}

// ---------------------------------------------------------------------------
// K0: transposes + temperature. grid 64 x 256. one thread per pixel.
//   xT  [y][64] bf16, xeT [y][32] f32, yeT [y][32] f32, tinv[y] = exp(-boxsum(lt)/49)
// ---------------------------------------------------------------------------
__global__ __launch_bounds__(256) void k_prep(
        const float* __restrict__ x, const float* __restrict__ xe,
        const float* __restrict__ ye, const float* __restrict__ lt,
        u16* __restrict__ xT, float* __restrict__ xeT,
        float* __restrict__ yeT, float* __restrict__ tinv) {
    int y = blockIdx.x * 256 + threadIdx.x;
    int py = y >> 7, px = y & 127;

    u16* xrow = xT + y * 64;
#pragma unroll
    for (int c0 = 0; c0 < 64; c0 += 8) {
        u32 w[4];
#pragma unroll
        for (int q = 0; q < 4; q++) {
            u16 a = f2bf(x[(c0 + 2 * q) * HW + y]);
            u16 b = f2bf(x[(c0 + 2 * q + 1) * HW + y]);
            w[q] = (u32)a | ((u32)b << 16);
        }
        *reinterpret_cast<uint4*>(xrow + c0) = make_uint4(w[0], w[1], w[2], w[3]);
    }
#pragma unroll
    for (int e0 = 0; e0 < 32; e0 += 4) {
        float4 v = make_float4(xe[(e0 + 0) * HW + y], xe[(e0 + 1) * HW + y],
                               xe[(e0 + 2) * HW + y], xe[(e0 + 3) * HW + y]);
        *reinterpret_cast<float4*>(xeT + y * 32 + e0) = v;
        float4 u = make_float4(ye[(e0 + 0) * HW + y], ye[(e0 + 1) * HW + y],
                               ye[(e0 + 2) * HW + y], ye[(e0 + 3) * HW + y]);
        *reinterpret_cast<float4*>(yeT + y * 32 + e0) = u;
    }
    float s = 0.f;
    for (int dy = -3; dy <= 3; dy++)
        for (int dx = -3; dx <= 3; dx++) {
            int yy = py + dy, xx = px + dx;
            if ((unsigned)yy < 128u && (unsigned)xx < 128u) s += lt[yy * 128 + xx];
        }
    tinv[y] = __expf(-s * (1.0f / 49.0f));
}

// ---------------------------------------------------------------------------
// K1: fused diff2 + 7x7 boxsum -> logits[o][y] f32.
// grid (13 di-rows, 64 tiles of 16x16), 512 threads.
// halo pixels z = tile +-3; xs shift = (di-6, dj-6) staged with 6-halo in LDS.
// ---------------------------------------------------------------------------
__global__ __launch_bounds__(512) void k_logits(
        const float* __restrict__ xeT, const float* __restrict__ yeT,
        const float* __restrict__ tinv, float* __restrict__ logits) {
    __shared__ float s_xe[22 * 34 * 36];  // [zr*34+zc(+dj)][e 32 pad36]
    __shared__ float s_d2[22 * 22];
    __shared__ float s_hs[22 * 16];

    int di = blockIdx.x;
    int tile = blockIdx.y;
    int h0 = (tile >> 3) * 16, w0 = (tile & 7) * 16;
    int gr0 = h0 + di - 9, gc0 = w0 - 9;
    int tid = threadIdx.x;

    for (int idx = tid; idx < 22 * 34 * 8; idx += 512) {
        int cell = idx >> 3, ch = idx & 7;
        int r = cell / 34, c = cell - r * 34;
        int gy = gr0 + r, gx = gc0 + c;
        float4 v = make_float4(0.f, 0.f, 0.f, 0.f);
        if ((unsigned)gy < 128u && (unsigned)gx < 128u)
            v = *reinterpret_cast<const float4*>(xeT + (gy * 128 + gx) * 32 + ch * 4);
        *reinterpret_cast<float4*>(s_xe + cell * 36 + ch * 4) = v;
    }

    int hp = tid;
    int zr = hp / 22, zc = hp - zr * 22;
    int gy = h0 - 3 + zr, gx = w0 - 3 + zc;
    bool zin = (hp < 484) && ((unsigned)gy < 128u) && ((unsigned)gx < 128u);
    float4 yr[8];
#pragma unroll
    for (int ch = 0; ch < 8; ch++) yr[ch] = make_float4(0.f, 0.f, 0.f, 0.f);
    if (zin) {
#pragma unroll
        for (int ch = 0; ch < 8; ch++)
            yr[ch] = *reinterpret_cast<const float4*>(yeT + (gy * 128 + gx) * 32 + ch * 4);
    }
    __syncthreads();

    for (int dj = 0; dj < 13; dj++) {
        if (hp < 484) {
            float d2 = 0.f;
            if (zin) {
                const float* base = s_xe + (zr * 34 + zc + dj) * 36;
#pragma unroll
                for (int ch = 0; ch < 8; ch++) {
                    float4 q = *reinterpret_cast<const float4*>(base + ch * 4);
                    float a = yr[ch].x - q.x, b = yr[ch].y - q.y;
                    float c2 = yr[ch].z - q.z, d = yr[ch].w - q.w;
                    d2 += a * a; d2 += b * b; d2 += c2 * c2; d2 += d * d;
                }
            }
            s_d2[hp] = d2;
        }
        __syncthreads();
        if (tid < 352) {  // horizontal: 22 halo rows x 16 out cols
            int r = tid >> 4, c = tid & 15;
            float s = 0.f;
#pragma unroll
            for (int d = 0; d < 7; d++) s += s_d2[r * 22 + c + d];
            s_hs[r * 16 + c] = s;
        }
        __syncthreads();
        if (tid < 256) {  // vertical: 16x16 outputs
            int i = tid >> 4, jj = tid & 15;
            float s = 0.f;
#pragma unroll
            for (int d = 0; d < 7; d++) s += s_hs[(i + d) * 16 + jj];
            int y = (h0 + i) * 128 + (w0 + jj);
            int o = di * 13 + dj;
            logits[o * HW + y] = -tinv[y] * s;
        }
        __syncthreads();
    }
}

// ---------------------------------------------------------------------------
// K2: K=7 rounds of exclusion softmax over O=169. grid 512 x 256.
// 32 pixels/block, 8 lanes per pixel (o strided by 8), logits AND the packed
// per-round weights held in registers; each (o,y) 16B cell written ONCE.
// ---------------------------------------------------------------------------
__global__ __launch_bounds__(256) void k_softmax(
        const float* __restrict__ logits, u16* __restrict__ Wkt) {
    __shared__ float s_lg[169 * 34];
    int tid = threadIdx.x;
    int y0 = blockIdx.x * 32;
    for (int idx = tid; idx < 169 * 32; idx += 256) {
        int o = idx >> 5, p = idx & 31;
        s_lg[o * 34 + p] = logits[o * HW + y0 + p];
    }
    __syncthreads();
    int pix = tid >> 3, t = tid & 7;
    int y = y0 + pix;
    float l[22];
#pragma unroll
    for (int j = 0; j < 22; j++) {
        int o = t + 8 * j;
        l[j] = (o < 169) ? s_lg[o * 34 + pix] : -3e38f;
    }
    u32 wp0[22], wp1[22], wp2[22], wp3[22];
#pragma unroll
    for (int j = 0; j < 22; j++) { wp0[j] = 0u; wp1[j] = 0u; wp2[j] = 0u; wp3[j] = 0u; }

    float e[22];
#pragma unroll
    for (int k = 0; k < 7; k++) {
        float m = -3e38f;
#pragma unroll
        for (int j = 0; j < 22; j++) m = fmaxf(m, l[j]);
        m = fmaxf(m, __shfl_xor(m, 1));
        m = fmaxf(m, __shfl_xor(m, 2));
        m = fmaxf(m, __shfl_xor(m, 4));
        float s = 0.f;
#pragma unroll
        for (int j = 0; j < 22; j++) { e[j] = __expf(l[j] - m); s += e[j]; }
        s += __shfl_xor(s, 1);
        s += __shfl_xor(s, 2);
        s += __shfl_xor(s, 4);
        float rs = 1.0f / s;
#pragma unroll
        for (int j = 0; j < 22; j++) {
            float w = e[j] * rs;
            u32 h = (u32)f2bf(w);
            if (k == 0) wp0[j] |= h;
            else if (k == 1) wp0[j] |= h << 16;
            else if (k == 2) wp1[j] |= h;
            else if (k == 3) wp1[j] |= h << 16;
            else if (k == 4) wp2[j] |= h;
            else if (k == 5) wp2[j] |= h << 16;
            else wp3[j] |= h;
            if (k < 6) l[j] += __logf(fmaxf(1.0f - w, 1e-6f));
        }
    }
#pragma unroll
    for (int j = 0; j < 22; j++) {
        int o = t + 8 * j;
        if (o < 169)
            *reinterpret_cast<uint4*>(Wkt + (o * HW + y) * 8) =
                make_uint4(wp0[j], wp1[j], wp2[j], wp3[j]);
    }
}

// ---------------------------------------------------------------------------
// K2b: 7x7 boxsum of Wkt -> WsT[o][y][k8] bf16. grid (169, 16 tiles of 32x32).
// separable sliding-window, vectorized over packed k.
// ---------------------------------------------------------------------------
__global__ __launch_bounds__(256) void k_wsum(
        const u16* __restrict__ Wkt, u16* __restrict__ WsT) {
    __shared__ u16 s_w[38 * 38 * 8];
    __shared__ float s_v[32 * 38 * 8];
    int o = blockIdx.x;
    int tile = blockIdx.y;
    int h0 = (tile >> 2) * 32, w0 = (tile & 3) * 32;
    int tid = threadIdx.x;

    for (int idx = tid; idx < 38 * 38; idx += 256) {
        int r = idx / 38, c = idx - r * 38;
        int gy = h0 - 3 + r, gx = w0 - 3 + c;
        uint4 v = make_uint4(0u, 0u, 0u, 0u);
        if ((unsigned)gy < 128u && (unsigned)gx < 128u)
            v = *reinterpret_cast<const uint4*>(Wkt + (o * HW + gy * 128 + gx) * 8);
        *reinterpret_cast<uint4*>(s_w + idx * 8) = v;
    }
    __syncthreads();

    if (tid < 152) {  // vertical: 38 cols x 4 groups of 8 out-rows
        int c = tid >> 2, g = tid & 3;
        int r0 = g * 8;
        float acc[7];
#pragma unroll
        for (int k = 0; k < 7; k++) acc[k] = 0.f;
#pragma unroll
        for (int d = 0; d < 7; d++) {
            uint4 q = *reinterpret_cast<const uint4*>(s_w + ((r0 + d) * 38 + c) * 8);
            acc[0] += bf2f((u16)(q.x & 0xffffu)); acc[1] += bf2f((u16)(q.x >> 16));
            acc[2] += bf2f((u16)(q.y & 0xffffu)); acc[3] += bf2f((u16)(q.y >> 16));
            acc[4] += bf2f((u16)(q.z & 0xffffu)); acc[5] += bf2f((u16)(q.z >> 16));
            acc[6] += bf2f((u16)(q.w & 0xffffu));
        }
#pragma unroll
        for (int k = 0; k < 7; k++) s_v[(r0 * 38 + c) * 8 + k] = acc[k];
        for (int i = 1; i < 8; i++) {
            uint4 qn = *reinterpret_cast<const uint4*>(s_w + ((r0 + i + 6) * 38 + c) * 8);
            uint4 qo = *reinterpret_cast<const uint4*>(s_w + ((r0 + i - 1) * 38 + c) * 8);
            acc[0] += bf2f((u16)(qn.x & 0xffffu)) - bf2f((u16)(qo.x & 0xffffu));
            acc[1] += bf2f((u16)(qn.x >> 16)) - bf2f((u16)(qo.x >> 16));
            acc[2] += bf2f((u16)(qn.y & 0xffffu)) - bf2f((u16)(qo.y & 0xffffu));
            acc[3] += bf2f((u16)(qn.y >> 16)) - bf2f((u16)(qo.y >> 16));
            acc[4] += bf2f((u16)(qn.z & 0xffffu)) - bf2f((u16)(qo.z & 0xffffu));
            acc[5] += bf2f((u16)(qn.z >> 16)) - bf2f((u16)(qo.z >> 16));
            acc[6] += bf2f((u16)(qn.w & 0xffffu)) - bf2f((u16)(qo.w & 0xffffu));
#pragma unroll
            for (int k = 0; k < 7; k++) s_v[((r0 + i) * 38 + c) * 8 + k] = acc[k];
        }
    }
    __syncthreads();

    if (tid < 128) {  // horizontal: 32 rows x 4 groups of 8 out-cols
        int r = tid >> 2, g = tid & 3;
        int c0 = g * 8;
        float acc[7];
#pragma unroll
        for (int k = 0; k < 7; k++) acc[k] = 0.f;
        for (int d = 0; d < 7; d++) {
#pragma unroll
            for (int k = 0; k < 7; k++) acc[k] += s_v[(r * 38 + c0 + d) * 8 + k];
        }
        for (int i = 0; i < 8; i++) {
            if (i > 0) {
#pragma unroll
                for (int k = 0; k < 7; k++)
                    acc[k] += s_v[(r * 38 + c0 + i + 6) * 8 + k] - s_v[(r * 38 + c0 + i - 1) * 8 + k];
            }
            u32 p0 = (u32)f2bf(acc[0]) | ((u32)f2bf(acc[1]) << 16);
            u32 p1 = (u32)f2bf(acc[2]) | ((u32)f2bf(acc[3]) << 16);
            u32 p2 = (u32)f2bf(acc[4]) | ((u32)f2bf(acc[5]) << 16);
            u32 p3 = (u32)f2bf(acc[6]);
            int y = (h0 + r) * 128 + (w0 + c0 + i);
            *reinterpret_cast<uint4*>(WsT + (o * HW + y) * 8) = make_uint4(p0, p1, p2, p3);
        }
    }
}

// ---------------------------------------------------------------------------
// K3 v3: aggregation. out[k,c,y] = sum_o WsT[o,y,k] * x[c, y+off(o)].
// grid 512 = 256 tiles (4x16 pix) x 2 c-halves; 512 thr = 64 pix x 8 cc(4ch).
// No loop barriers: w is read straight from global (L1-broadcast across cc
// waves) with 1-deep prefetch; x staged once in LDS ([448][44] u16, 2-way
// max bank aliasing = free). acc[7][4] in registers.
// ---------------------------------------------------------------------------
__global__ __launch_bounds__(512) void k_agg(
        const u16* __restrict__ xT, const u16* __restrict__ WsT,
        float* __restrict__ out) {
    __shared__ u16 s_x[448 * 44];     // [16r x 28c][32ch pad 44]
    int tb = blockIdx.x & 255;
    int half = blockIdx.x >> 8;       // c-half: channels half*32 .. half*32+31
    int h0 = (tb >> 3) * 4, w0 = (tb & 7) * 16;
    int tid = threadIdx.x;

    // stage x half-channels: 448 cells x 32ch, uint2 (4ch) per thread-step
    for (int idx = tid; idx < 448 * 8; idx += 512) {
        int cell = idx >> 3, chq = idx & 7;
        int r = cell / 28, c = cell - r * 28;
        int gy = h0 - 6 + r, gx = w0 - 6 + c;
        uint2 v = make_uint2(0u, 0u);
        if ((unsigned)gy < 128u && (unsigned)gx < 128u)
            v = *reinterpret_cast<const uint2*>(xT + (gy * 128 + gx) * 64 + half * 32 + chq * 4);
        *reinterpret_cast<uint2*>(s_x + cell * 44 + chq * 4) = v;
    }
    __syncthreads();

    int cc = tid >> 6, pix = tid & 63;          // cc: 8 chunks of 4 ch
    int pr = pix >> 4, pc = pix & 15;
    int y = (h0 + pr) * 128 + (w0 + pc);
    const u16* wsrc = WsT + (size_t)y * 8;      // + o*HW*8 per o

    float acc[7][4];
#pragma unroll
    for (int k = 0; k < 7; k++)
#pragma unroll
        for (int q = 0; q < 4; q++) acc[k][q] = 0.f;

    int cell0 = pr * 28 + pc;                   // cell for (di=0,dj=0)
    uint4 wreg = *reinterpret_cast<const uint4*>(wsrc);  // o = 0

    int di = 0, dj = 0;
#pragma unroll 1
    for (int o = 0; o < 169; o++) {
        // prefetch next o's weights while computing this one
        uint4 wnext;
        if (o < 168)
            wnext = *reinterpret_cast<const uint4*>(wsrc + (size_t)(o + 1) * HW * 8);
        float wv[7];
        wv[0] = bf2f((u16)(wreg.x & 0xffffu)); wv[1] = bf2f((u16)(wreg.x >> 16));
        wv[2] = bf2f((u16)(wreg.y & 0xffffu)); wv[3] = bf2f((u16)(wreg.y >> 16));
        wv[4] = bf2f((u16)(wreg.z & 0xffffu)); wv[5] = bf2f((u16)(wreg.z >> 16));
        wv[6] = bf2f((u16)(wreg.w & 0xffffu));

        int cell = cell0 + di * 28 + dj;
        uint2 xa = *reinterpret_cast<const uint2*>(s_x + cell * 44 + cc * 4);
        float xv[4];
        xv[0] = bf2f((u16)(xa.x & 0xffffu)); xv[1] = bf2f((u16)(xa.x >> 16));
        xv[2] = bf2f((u16)(xa.y & 0xffffu)); xv[3] = bf2f((u16)(xa.y >> 16));
#pragma unroll
        for (int k = 0; k < 7; k++)
#pragma unroll
            for (int q = 0; q < 4; q++)
                acc[k][q] = fmaf(wv[k], xv[q], acc[k][q]);

        wreg = wnext;
        if (++dj == 13) { dj = 0; ++di; }
    }

    int cbase = half * 32 + cc * 4;
#pragma unroll
    for (int k = 0; k < 7; k++)
#pragma unroll
        for (int q = 0; q < 4; q++)
            out[(k * 64 + cbase + q) * HW + y] = acc[k][q];
}

// ---------------------------------------------------------------------------
extern "C" void kernel_launch(void* const* d_in, const int* in_sizes, int n_in,
                              void* d_out, int out_size, void* d_ws, size_t ws_size,
                              hipStream_t stream) {
    (void)in_sizes; (void)n_in; (void)out_size; (void)ws_size;
    const float* x  = (const float*)d_in[0];
    const float* xe = (const float*)d_in[1];
    const float* ye = (const float*)d_in[2];
    const float* lt = (const float*)d_in[3];
    float* out = (float*)d_out;
    char* ws = (char*)d_ws;

    u16*   xT     = (u16*)(ws + 0);            //  2,097,152 B
    float* xeT    = (float*)(ws + 2097152u);   //  2,097,152
    float* yeT    = (float*)(ws + 4194304u);   //  2,097,152
    float* tinv   = (float*)(ws + 6291456u);   //     65,536
    float* logits = (float*)(ws + 6356992u);   // 11,075,584
    u16*   Wkt    = (u16*)(ws + 17432576u);    // 44,302,336
    u16*   WsT    = (u16*)(ws + 61734912u);    // 44,302,336 -> ends 106,037,248

    k_prep<<<64, 256, 0, stream>>>(x, xe, ye, lt, xT, xeT, yeT, tinv);
    k_logits<<<dim3(13, 64), 512, 0, stream>>>(xeT, yeT, tinv, logits);
    k_softmax<<<512, 256, 0, stream>>>(logits, Wkt);
    k_wsum<<<dim3(169, 16), 256, 0, stream>>>(Wkt, WsT);
    k_agg<<<512, 512, 0, stream>>>(xT, WsT, out);
}

// Round 4
// 191.649 us; speedup vs baseline: 1.0597x; 1.0597x over previous
//
#include <hip/hip_runtime.h>
#include <hip/hip_bf16.h>
#include <hip/hip_fp16.h>

// N3 aggregation: C=64, E=32, H=W=128, K=7, PS=7 (PR=3), WS=13 (WR=6), O=169
#define HW 16384

using u16 = unsigned short;
using u32 = unsigned int;

__device__ __forceinline__ float bf2f(u16 u) {
    u32 x = ((u32)u) << 16;
    return __uint_as_float(x);
}
__device__ __forceinline__ u16 f2h(float f) {
    __half h = __float2half(f);
    return __builtin_bit_cast(u16, h);
}
__device__ __forceinline__ float h2f(u16 u) {
    __half h = __builtin_bit_cast(__half, u);
    return __half2float(h);
}
// acc += a.x*b.x + a.y*b.y  (f16 pairs, f32 accumulate)
__device__ __forceinline__ void dot2acc(float& acc, u32 a, u32 b) {
    asm("v_dot2_f32_f16 %0, %1, %2, %0" : "+v"(acc) : "v"(a), "v"(b));
}

// ---------------------------------------------------------------------------
// K0: transposes + temperature. grid 64 x 256. one thread per pixel.
//   xh [c][128][128] f16 (channel-major), xeT/yeT [y][32] f32,
//   tinv[y] = exp(-boxsum(lt)/49)
// ---------------------------------------------------------------------------
__global__ __launch_bounds__(256) void k_prep(
        const float* __restrict__ x, const float* __restrict__ xe,
        const float* __restrict__ ye, const float* __restrict__ lt,
        u16* __restrict__ xh, float* __restrict__ xeT,
        float* __restrict__ yeT, float* __restrict__ tinv) {
    int y = blockIdx.x * 256 + threadIdx.x;
    int py = y >> 7, px = y & 127;

#pragma unroll
    for (int c = 0; c < 64; c++)
        xh[c * HW + y] = f2h(x[c * HW + y]);

#pragma unroll
    for (int e0 = 0; e0 < 32; e0 += 4) {
        float4 v = make_float4(xe[(e0 + 0) * HW + y], xe[(e0 + 1) * HW + y],
                               xe[(e0 + 2) * HW + y], xe[(e0 + 3) * HW + y]);
        *reinterpret_cast<float4*>(xeT + y * 32 + e0) = v;
        float4 u = make_float4(ye[(e0 + 0) * HW + y], ye[(e0 + 1) * HW + y],
                               ye[(e0 + 2) * HW + y], ye[(e0 + 3) * HW + y]);
        *reinterpret_cast<float4*>(yeT + y * 32 + e0) = u;
    }
    float s = 0.f;
    for (int dy = -3; dy <= 3; dy++)
        for (int dx = -3; dx <= 3; dx++) {
            int yy = py + dy, xx = px + dx;
            if ((unsigned)yy < 128u && (unsigned)xx < 128u) s += lt[yy * 128 + xx];
        }
    tinv[y] = __expf(-s * (1.0f / 49.0f));
}

// ---------------------------------------------------------------------------
// K1: fused diff2 + 7x7 boxsum -> logits[o][y] f32.
// grid (13 di-rows, 64 tiles of 16x16), 512 threads.
// ---------------------------------------------------------------------------
__global__ __launch_bounds__(512) void k_logits(
        const float* __restrict__ xeT, const float* __restrict__ yeT,
        const float* __restrict__ tinv, float* __restrict__ logits) {
    __shared__ float s_xe[22 * 34 * 36];  // [zr*34+zc(+dj)][e 32 pad36]
    __shared__ float s_d2[22 * 22];
    __shared__ float s_hs[22 * 16];

    int di = blockIdx.x;
    int tile = blockIdx.y;
    int h0 = (tile >> 3) * 16, w0 = (tile & 7) * 16;
    int gr0 = h0 + di - 9, gc0 = w0 - 9;
    int tid = threadIdx.x;

    for (int idx = tid; idx < 22 * 34 * 8; idx += 512) {
        int cell = idx >> 3, ch = idx & 7;
        int r = cell / 34, c = cell - r * 34;
        int gy = gr0 + r, gx = gc0 + c;
        float4 v = make_float4(0.f, 0.f, 0.f, 0.f);
        if ((unsigned)gy < 128u && (unsigned)gx < 128u)
            v = *reinterpret_cast<const float4*>(xeT + (gy * 128 + gx) * 32 + ch * 4);
        *reinterpret_cast<float4*>(s_xe + cell * 36 + ch * 4) = v;
    }

    int hp = tid;
    int zr = hp / 22, zc = hp - zr * 22;
    int gy = h0 - 3 + zr, gx = w0 - 3 + zc;
    bool zin = (hp < 484) && ((unsigned)gy < 128u) && ((unsigned)gx < 128u);
    float4 yr[8];
#pragma unroll
    for (int ch = 0; ch < 8; ch++) yr[ch] = make_float4(0.f, 0.f, 0.f, 0.f);
    if (zin) {
#pragma unroll
        for (int ch = 0; ch < 8; ch++)
            yr[ch] = *reinterpret_cast<const float4*>(yeT + (gy * 128 + gx) * 32 + ch * 4);
    }
    __syncthreads();

    for (int dj = 0; dj < 13; dj++) {
        if (hp < 484) {
            float d2 = 0.f;
            if (zin) {
                const float* base = s_xe + (zr * 34 + zc + dj) * 36;
#pragma unroll
                for (int ch = 0; ch < 8; ch++) {
                    float4 q = *reinterpret_cast<const float4*>(base + ch * 4);
                    float a = yr[ch].x - q.x, b = yr[ch].y - q.y;
                    float c2 = yr[ch].z - q.z, d = yr[ch].w - q.w;
                    d2 += a * a; d2 += b * b; d2 += c2 * c2; d2 += d * d;
                }
            }
            s_d2[hp] = d2;
        }
        __syncthreads();
        if (tid < 352) {  // horizontal: 22 halo rows x 16 out cols
            int r = tid >> 4, c = tid & 15;
            float s = 0.f;
#pragma unroll
            for (int d = 0; d < 7; d++) s += s_d2[r * 22 + c + d];
            s_hs[r * 16 + c] = s;
        }
        __syncthreads();
        if (tid < 256) {  // vertical: 16x16 outputs
            int i = tid >> 4, jj = tid & 15;
            float s = 0.f;
#pragma unroll
            for (int d = 0; d < 7; d++) s += s_hs[(i + d) * 16 + jj];
            int y = (h0 + i) * 128 + (w0 + jj);
            int o = di * 13 + dj;
            logits[o * HW + y] = -tinv[y] * s;
        }
        __syncthreads();
    }
}

// ---------------------------------------------------------------------------
// K2: K=7 rounds of exclusion softmax over O=169. grid 512 x 256.
// 32 pixels/block, 8 lanes per pixel; logits AND packed per-round weights in
// registers; each (o,y) 16B cell written ONCE. Output now f16.
// ---------------------------------------------------------------------------
__global__ __launch_bounds__(256) void k_softmax(
        const float* __restrict__ logits, u16* __restrict__ Wkt) {
    __shared__ float s_lg[169 * 34];
    int tid = threadIdx.x;
    int y0 = blockIdx.x * 32;
    for (int idx = tid; idx < 169 * 32; idx += 256) {
        int o = idx >> 5, p = idx & 31;
        s_lg[o * 34 + p] = logits[o * HW + y0 + p];
    }
    __syncthreads();
    int pix = tid >> 3, t = tid & 7;
    int y = y0 + pix;
    float l[22];
#pragma unroll
    for (int j = 0; j < 22; j++) {
        int o = t + 8 * j;
        l[j] = (o < 169) ? s_lg[o * 34 + pix] : -3e38f;
    }
    u32 wp0[22], wp1[22], wp2[22], wp3[22];
#pragma unroll
    for (int j = 0; j < 22; j++) { wp0[j] = 0u; wp1[j] = 0u; wp2[j] = 0u; wp3[j] = 0u; }

    float e[22];
#pragma unroll
    for (int k = 0; k < 7; k++) {
        float m = -3e38f;
#pragma unroll
        for (int j = 0; j < 22; j++) m = fmaxf(m, l[j]);
        m = fmaxf(m, __shfl_xor(m, 1));
        m = fmaxf(m, __shfl_xor(m, 2));
        m = fmaxf(m, __shfl_xor(m, 4));
        float s = 0.f;
#pragma unroll
        for (int j = 0; j < 22; j++) { e[j] = __expf(l[j] - m); s += e[j]; }
        s += __shfl_xor(s, 1);
        s += __shfl_xor(s, 2);
        s += __shfl_xor(s, 4);
        float rs = 1.0f / s;
#pragma unroll
        for (int j = 0; j < 22; j++) {
            float w = e[j] * rs;
            u32 h = (u32)f2h(w);
            if (k == 0) wp0[j] |= h;
            else if (k == 1) wp0[j] |= h << 16;
            else if (k == 2) wp1[j] |= h;
            else if (k == 3) wp1[j] |= h << 16;
            else if (k == 4) wp2[j] |= h;
            else if (k == 5) wp2[j] |= h << 16;
            else wp3[j] |= h;
            if (k < 6) l[j] += __logf(fmaxf(1.0f - w, 1e-6f));
        }
    }
#pragma unroll
    for (int j = 0; j < 22; j++) {
        int o = t + 8 * j;
        if (o < 169)
            *reinterpret_cast<uint4*>(Wkt + (o * HW + y) * 8) =
                make_uint4(wp0[j], wp1[j], wp2[j], wp3[j]);
    }
}

// ---------------------------------------------------------------------------
// K2b: 7x7 boxsum of Wkt(f16) -> WsT[o][y][k8] f16. grid (169, 16 tiles 32x32).
// ---------------------------------------------------------------------------
__global__ __launch_bounds__(256) void k_wsum(
        const u16* __restrict__ Wkt, u16* __restrict__ WsT) {
    __shared__ u16 s_w[38 * 38 * 8];
    __shared__ float s_v[32 * 38 * 8];
    int o = blockIdx.x;
    int tile = blockIdx.y;
    int h0 = (tile >> 2) * 32, w0 = (tile & 3) * 32;
    int tid = threadIdx.x;

    for (int idx = tid; idx < 38 * 38; idx += 256) {
        int r = idx / 38, c = idx - r * 38;
        int gy = h0 - 3 + r, gx = w0 - 3 + c;
        uint4 v = make_uint4(0u, 0u, 0u, 0u);
        if ((unsigned)gy < 128u && (unsigned)gx < 128u)
            v = *reinterpret_cast<const uint4*>(Wkt + (o * HW + gy * 128 + gx) * 8);
        *reinterpret_cast<uint4*>(s_w + idx * 8) = v;
    }
    __syncthreads();

    if (tid < 152) {  // vertical: 38 cols x 4 groups of 8 out-rows
        int c = tid >> 2, g = tid & 3;
        int r0 = g * 8;
        float acc[7];
#pragma unroll
        for (int k = 0; k < 7; k++) acc[k] = 0.f;
#pragma unroll
        for (int d = 0; d < 7; d++) {
            uint4 q = *reinterpret_cast<const uint4*>(s_w + ((r0 + d) * 38 + c) * 8);
            acc[0] += h2f((u16)(q.x & 0xffffu)); acc[1] += h2f((u16)(q.x >> 16));
            acc[2] += h2f((u16)(q.y & 0xffffu)); acc[3] += h2f((u16)(q.y >> 16));
            acc[4] += h2f((u16)(q.z & 0xffffu)); acc[5] += h2f((u16)(q.z >> 16));
            acc[6] += h2f((u16)(q.w & 0xffffu));
        }
#pragma unroll
        for (int k = 0; k < 7; k++) s_v[(r0 * 38 + c) * 8 + k] = acc[k];
        for (int i = 1; i < 8; i++) {
            uint4 qn = *reinterpret_cast<const uint4*>(s_w + ((r0 + i + 6) * 38 + c) * 8);
            uint4 qo = *reinterpret_cast<const uint4*>(s_w + ((r0 + i - 1) * 38 + c) * 8);
            acc[0] += h2f((u16)(qn.x & 0xffffu)) - h2f((u16)(qo.x & 0xffffu));
            acc[1] += h2f((u16)(qn.x >> 16)) - h2f((u16)(qo.x >> 16));
            acc[2] += h2f((u16)(qn.y & 0xffffu)) - h2f((u16)(qo.y & 0xffffu));
            acc[3] += h2f((u16)(qn.y >> 16)) - h2f((u16)(qo.y >> 16));
            acc[4] += h2f((u16)(qn.z & 0xffffu)) - h2f((u16)(qo.z & 0xffffu));
            acc[5] += h2f((u16)(qn.z >> 16)) - h2f((u16)(qo.z >> 16));
            acc[6] += h2f((u16)(qn.w & 0xffffu)) - h2f((u16)(qo.w & 0xffffu));
#pragma unroll
            for (int k = 0; k < 7; k++) s_v[((r0 + i) * 38 + c) * 8 + k] = acc[k];
        }
    }
    __syncthreads();

    if (tid < 128) {  // horizontal: 32 rows x 4 groups of 8 out-cols
        int r = tid >> 2, g = tid & 3;
        int c0 = g * 8;
        float acc[7];
#pragma unroll
        for (int k = 0; k < 7; k++) acc[k] = 0.f;
        for (int d = 0; d < 7; d++) {
#pragma unroll
            for (int k = 0; k < 7; k++) acc[k] += s_v[(r * 38 + c0 + d) * 8 + k];
        }
        for (int i = 0; i < 8; i++) {
            if (i > 0) {
#pragma unroll
                for (int k = 0; k < 7; k++)
                    acc[k] += s_v[(r * 38 + c0 + i + 6) * 8 + k] - s_v[(r * 38 + c0 + i - 1) * 8 + k];
            }
            u32 p0 = (u32)f2h(acc[0]) | ((u32)f2h(acc[1]) << 16);
            u32 p1 = (u32)f2h(acc[2]) | ((u32)f2h(acc[3]) << 16);
            u32 p2 = (u32)f2h(acc[4]) | ((u32)f2h(acc[5]) << 16);
            u32 p3 = (u32)f2h(acc[6]);
            int y = (h0 + r) * 128 + (w0 + c0 + i);
            *reinterpret_cast<uint4*>(WsT + (o * HW + y) * 8) = make_uint4(p0, p1, p2, p3);
        }
    }
}

// ---------------------------------------------------------------------------
// K3 v4: aggregation via v_dot2_f32_f16.
// out[k,c,y] = sum_o WsT[o,y,k] * x[c, y+off(o)].
// grid 1024 = 256 tiles (4x16 pix) x 4 c-splits (16ch); 256 thr = 64 pix x 4 cc.
// x staged CHANNEL-MAJOR in LDS ([16ch][16r][32c] f16) so two adjacent-dj
// candidates' x values sit in one dword -> ds_read2_b32 + v_alignbit.
// w pairs built with v_perm from two b128 loads. dj paired (0,1)(2,3)..(12,zero).
// ---------------------------------------------------------------------------
#define SELLO 0x05040100u
#define SELHI 0x07060302u
__global__ __launch_bounds__(256, 4) void k_agg(
        const u16* __restrict__ xh, const u16* __restrict__ WsT,
        float* __restrict__ out) {
    __shared__ u16 s_x[16 * 16 * 32];   // [ch][r][c pad32] f16
    int tb = blockIdx.x & 255;
    int csplit = blockIdx.x >> 8;       // 16 channels per split
    int h0 = (tb >> 3) * 4, w0 = (tb & 7) * 16;
    int tid = threadIdx.x;

    // stage: 16ch x 16r x 4 chunks of 8 cols from channel-major global xh
    for (int it = tid; it < 1024; it += 256) {
        int ch = it >> 6;             // 0..15 (relative)
        int r = (it >> 2) & 15;       // 0..15
        int c0 = (it & 3) * 8;        // 0,8,16,24
        int gy = h0 - 6 + r, gx0 = w0 - 6 + c0;
        int gc = csplit * 16 + ch;
        uint4 v = make_uint4(0u, 0u, 0u, 0u);
        if ((unsigned)gy < 128u) {
            const u16* src = xh + (gc * 128 + gy) * 128;
            if (gx0 >= 0 && gx0 <= 120) {
                v = *reinterpret_cast<const uint4*>(src + gx0);
            } else {
                auto pk = [&](int gx) -> u32 {
                    u32 lo = ((unsigned)gx < 128u) ? (u32)src[gx] : 0u;
                    u32 hi = ((unsigned)(gx + 1) < 128u) ? (u32)src[gx + 1] : 0u;
                    return lo | (hi << 16);
                };
                v = make_uint4(pk(gx0), pk(gx0 + 2), pk(gx0 + 4), pk(gx0 + 6));
            }
        }
        *reinterpret_cast<uint4*>(s_x + (ch * 16 + r) * 32 + c0) = v;
    }
    __syncthreads();

    int cc = tid >> 6, pix = tid & 63;
    int pr = pix >> 4, pc = pix & 15;
    int y = (h0 + pr) * 128 + (w0 + pc);
    const u16* wsrc = WsT + (size_t)y * 8;
    const u32* s_x32 = reinterpret_cast<const u32*>(s_x);
    u32 sh = (u32)(pc & 1) * 16;        // alignbit shift, fixed per thread
    int cbase_dw = (pc >> 1);           // dword col base

    float acc[7][4];
#pragma unroll
    for (int k = 0; k < 7; k++)
#pragma unroll
        for (int q = 0; q < 4; q++) acc[k][q] = 0.f;

#pragma unroll 1
    for (int di = 0; di < 13; di++) {
        // hoist all 13 w-loads for this di-row (latencies overlap)
        uint4 WA[7], WB[7];
#pragma unroll
        for (int djp = 0; djp < 7; djp++) {
            int o0 = di * 13 + 2 * djp;
            WA[djp] = *reinterpret_cast<const uint4*>(wsrc + (size_t)o0 * (HW * 8));
            WB[djp] = (djp < 6)
                ? *reinterpret_cast<const uint4*>(wsrc + (size_t)(o0 + 1) * (HW * 8))
                : make_uint4(0u, 0u, 0u, 0u);
        }
        int rowb = (pr + di) * 16 + cbase_dw;   // dword row base (per ch add 256)
#pragma unroll
        for (int djp = 0; djp < 7; djp++) {
            u32 wp[7];
            wp[0] = __builtin_amdgcn_perm(WB[djp].x, WA[djp].x, SELLO);
            wp[1] = __builtin_amdgcn_perm(WB[djp].x, WA[djp].x, SELHI);
            wp[2] = __builtin_amdgcn_perm(WB[djp].y, WA[djp].y, SELLO);
            wp[3] = __builtin_amdgcn_perm(WB[djp].y, WA[djp].y, SELHI);
            wp[4] = __builtin_amdgcn_perm(WB[djp].z, WA[djp].z, SELLO);
            wp[5] = __builtin_amdgcn_perm(WB[djp].z, WA[djp].z, SELHI);
            wp[6] = __builtin_amdgcn_perm(WB[djp].w, WA[djp].w, SELLO);
#pragma unroll
            for (int q = 0; q < 4; q++) {
                const u32* p = s_x32 + ((cc * 4 + q) * 256 + rowb + djp);
                u32 d0 = p[0], d1 = p[1];
                u32 x2 = __builtin_amdgcn_alignbit(d1, d0, sh);
#pragma unroll
                for (int k = 0; k < 7; k++)
                    dot2acc(acc[k][q], wp[k], x2);
            }
        }
    }

    int cb = csplit * 16 + cc * 4;
#pragma unroll
    for (int k = 0; k < 7; k++)
#pragma unroll
        for (int q = 0; q < 4; q++)
            out[(k * 64 + cb + q) * HW + y] = acc[k][q];
}

// ---------------------------------------------------------------------------
extern "C" void kernel_launch(void* const* d_in, const int* in_sizes, int n_in,
                              void* d_out, int out_size, void* d_ws, size_t ws_size,
                              hipStream_t stream) {
    (void)in_sizes; (void)n_in; (void)out_size; (void)ws_size;
    const float* x  = (const float*)d_in[0];
    const float* xe = (const float*)d_in[1];
    const float* ye = (const float*)d_in[2];
    const float* lt = (const float*)d_in[3];
    float* out = (float*)d_out;
    char* ws = (char*)d_ws;

    u16*   xh     = (u16*)(ws + 0);            //  2,097,152 B (f16 [64][128][128])
    float* xeT    = (float*)(ws + 2097152u);   //  2,097,152
    float* yeT    = (float*)(ws + 4194304u);   //  2,097,152
    float* tinv   = (float*)(ws + 6291456u);   //     65,536
    float* logits = (float*)(ws + 6356992u);   // 11,075,584
    u16*   Wkt    = (u16*)(ws + 17432576u);    // 44,302,336 (f16)
    u16*   WsT    = (u16*)(ws + 61734912u);    // 44,302,336 (f16) -> ends 106,037,248

    k_prep<<<64, 256, 0, stream>>>(x, xe, ye, lt, xh, xeT, yeT, tinv);
    k_logits<<<dim3(13, 64), 512, 0, stream>>>(xeT, yeT, tinv, logits);
    k_softmax<<<512, 256, 0, stream>>>(logits, Wkt);
    k_wsum<<<dim3(169, 16), 256, 0, stream>>>(Wkt, WsT);
    k_agg<<<1024, 256, 0, stream>>>(xh, WsT, out);
}

// Round 5
// 181.131 us; speedup vs baseline: 1.1212x; 1.0581x over previous
//
#include <hip/hip_runtime.h>
#include <hip/hip_bf16.h>
#include <hip/hip_fp16.h>

// N3 aggregation: C=64, E=32, H=W=128, K=7, PS=7 (PR=3), WS=13 (WR=6), O=169
#define HW 16384

using u16 = unsigned short;
using u32 = unsigned int;
typedef __attribute__((ext_vector_type(2))) float f32x2;

__device__ __forceinline__ u16 f2h(float f) {
    __half h = __float2half(f);
    return __builtin_bit_cast(u16, h);
}
__device__ __forceinline__ float h2f(u16 u) {
    __half h = __builtin_bit_cast(__half, u);
    return __half2float(h);
}
// acc += a.x*b.x + a.y*b.y  (f16 pairs, f32 accumulate)
__device__ __forceinline__ void dot2acc(float& acc, u32 a, u32 b) {
    asm("v_dot2_f32_f16 %0, %1, %2, %0" : "+v"(acc) : "v"(a), "v"(b));
}

// ---------------------------------------------------------------------------
// K0: transposes + per-pixel norms. grid 64 x 256. one thread per pixel.
//   xh [c][128][128] f16, xeT/yeT [y][32] f32, nx[y]=|xe(y)|^2, ny[y]=|ye(y)|^2
// ---------------------------------------------------------------------------
__global__ __launch_bounds__(256) void k_prep(
        const float* __restrict__ x, const float* __restrict__ xe,
        const float* __restrict__ ye,
        u16* __restrict__ xh, float* __restrict__ xeT,
        float* __restrict__ yeT, float* __restrict__ nx, float* __restrict__ ny) {
    int y = blockIdx.x * 256 + threadIdx.x;

#pragma unroll
    for (int c = 0; c < 64; c++)
        xh[c * HW + y] = f2h(x[c * HW + y]);

    float sx = 0.f, sy = 0.f;
#pragma unroll
    for (int e0 = 0; e0 < 32; e0 += 4) {
        float4 v = make_float4(xe[(e0 + 0) * HW + y], xe[(e0 + 1) * HW + y],
                               xe[(e0 + 2) * HW + y], xe[(e0 + 3) * HW + y]);
        *reinterpret_cast<float4*>(xeT + y * 32 + e0) = v;
        sx += v.x * v.x + v.y * v.y + v.z * v.z + v.w * v.w;
        float4 u = make_float4(ye[(e0 + 0) * HW + y], ye[(e0 + 1) * HW + y],
                               ye[(e0 + 2) * HW + y], ye[(e0 + 3) * HW + y]);
        *reinterpret_cast<float4*>(yeT + y * 32 + e0) = u;
        sy += u.x * u.x + u.y * u.y + u.z * u.z + u.w * u.w;
    }
    nx[y] = sx;
    ny[y] = sy;
}

// ---------------------------------------------------------------------------
// K0b: st[y] = (tinv, tinv*Sy) where tinv = exp(-boxsum(lt)/49), Sy = boxsum(ny).
// grid 64 x 256, one thread per pixel, 49-tap guarded (L2-resident inputs).
// ---------------------------------------------------------------------------
__global__ __launch_bounds__(256) void k_norms(
        const float* __restrict__ ny, const float* __restrict__ lt,
        float2* __restrict__ st) {
    int y = blockIdx.x * 256 + threadIdx.x;
    int py = y >> 7, px = y & 127;
    float s = 0.f, t = 0.f;
    for (int dy = -3; dy <= 3; dy++)
        for (int dx = -3; dx <= 3; dx++) {
            int yy = py + dy, xx = px + dx;
            if ((unsigned)yy < 128u && (unsigned)xx < 128u) {
                int p = yy * 128 + xx;
                s += ny[p];
                t += lt[p];
            }
        }
    float tinv = __expf(-t * (1.0f / 49.0f));
    st[y] = make_float2(tinv, tinv * s);
}

// ---------------------------------------------------------------------------
// K1 v2: logits[o][y] = -tinv*( Sy(y) + boxsum_z( nx(z+o) - 2*ye(z).xe(z+o) ) ).
// grid (13 di, 64 tiles of 16x16), 1024 threads.
// xe halo (22x34 cells x 32 f32) staged chunk-XOR-swizzled (<=2-way banks);
// nx staged per cell. 484 compute threads hold ye in regs, fully-unrolled
// dj loop (8 swizzled b128 + 16 pk_fma per dj), d2 written per-dj.
// Then one hsum + one vsum phase over all 13 planes. 5 barriers total.
// ---------------------------------------------------------------------------
__global__ __launch_bounds__(1024) void k_logits(
        const float* __restrict__ xeT, const float* __restrict__ yeT,
        const float* __restrict__ nxg, const float2* __restrict__ st,
        float* __restrict__ logits) {
#pragma clang fp contract(fast)
    __shared__ __align__(16) char arena[123904];
    float* s_xe = (float*)arena;              // 748 cells * 32 dw, swizzled
    float* s_nx = (float*)(arena + 95744);    // 748
    float* s_d2 = (float*)(arena + 98736);    // 13 * 484
    float* s_hs = (float*)arena;              // overlay after compute: 13*22*16

    int di = blockIdx.x;
    int tile = blockIdx.y;
    int h0 = (tile >> 3) * 16, w0 = (tile & 7) * 16;
    int gr0 = h0 + di - 9, gc0 = w0 - 9;
    int tid = threadIdx.x;

    // stage xe halo: 748 cells x 8 float4-chunks, chunk-swizzled
    for (int idx = tid; idx < 748 * 8; idx += 1024) {
        int cell = idx >> 3, q = idx & 7;
        int r = cell / 34, c = cell - r * 34;
        int gy = gr0 + r, gx = gc0 + c;
        float4 v = make_float4(0.f, 0.f, 0.f, 0.f);
        if ((unsigned)gy < 128u && (unsigned)gx < 128u)
            v = *reinterpret_cast<const float4*>(xeT + (size_t)(gy * 128 + gx) * 32 + q * 4);
        *reinterpret_cast<float4*>(s_xe + cell * 32 + ((q ^ (cell & 7)) << 2)) = v;
    }
    for (int idx = tid; idx < 748; idx += 1024) {
        int r = idx / 34, c = idx - r * 34;
        int gy = gr0 + r, gx = gc0 + c;
        float v = 0.f;
        if ((unsigned)gy < 128u && (unsigned)gx < 128u) v = nxg[gy * 128 + gx];
        s_nx[idx] = v;
    }
    __syncthreads();

    if (tid < 484) {
        int zr = tid / 22, zc = tid - zr * 22;
        int gy = h0 - 3 + zr, gx = w0 - 3 + zc;
        bool zin = ((unsigned)gy < 128u) && ((unsigned)gx < 128u);
        f32x2 yv[16];
#pragma unroll
        for (int j = 0; j < 16; j++) yv[j] = (f32x2){0.f, 0.f};
        if (zin) {
            const float* yp = yeT + (size_t)(gy * 128 + gx) * 32;
#pragma unroll
            for (int j = 0; j < 8; j++) {
                float4 t = *reinterpret_cast<const float4*>(yp + j * 4);
                yv[2 * j] = (f32x2){t.x, t.y};
                yv[2 * j + 1] = (f32x2){t.z, t.w};
            }
        }
        int cell0 = zr * 34 + zc;
#pragma unroll
        for (int dj = 0; dj < 13; dj++) {
            int cell = cell0 + dj;
            const float* bp = s_xe + cell * 32;
            int sw = cell & 7;
            f32x2 a0 = {0.f, 0.f}, a1 = {0.f, 0.f};
#pragma unroll
            for (int q = 0; q < 8; q++) {
                float4 xv = *reinterpret_cast<const float4*>(bp + ((q ^ sw) << 2));
                a0 += ((f32x2){xv.x, xv.y}) * yv[2 * q];
                a1 += ((f32x2){xv.z, xv.w}) * yv[2 * q + 1];
            }
            float cr = a0.x + a0.y + a1.x + a1.y;
            float d2v = fmaf(-2.f, cr, s_nx[cell]);
            s_d2[dj * 484 + tid] = zin ? d2v : 0.f;
        }
    }
    __syncthreads();

    // horizontal 7-tap: 13 x 22 x 16 -> s_hs (overlays s_xe)
    for (int idx = tid; idx < 4576; idx += 1024) {
        int dj = idx / 352, rem = idx - dj * 352;
        int r = rem >> 4, c = rem & 15;
        const float* p = s_d2 + dj * 484 + r * 22 + c;
        float s = p[0] + p[1] + p[2] + p[3] + p[4] + p[5] + p[6];
        s_hs[(dj * 22 + r) * 16 + c] = s;
    }
    __syncthreads();

    // vertical 7-tap + Sy/tinv fold + store: 13 x 16 x 16
    for (int idx = tid; idx < 3328; idx += 1024) {
        int dj = idx >> 8, rem = idx & 255;
        int i = rem >> 4, jj = rem & 15;
        const float* p = s_hs + (dj * 22 + i) * 16 + jj;
        float s = p[0] + p[16] + p[32] + p[48] + p[64] + p[80] + p[96];
        int y = (h0 + i) * 128 + (w0 + jj);
        float2 ab = st[y];
        logits[(di * 13 + dj) * HW + y] = -fmaf(ab.x, s, ab.y);
    }
}

// ---------------------------------------------------------------------------
// K2: K=7 rounds of exclusion softmax over O=169. grid 512 x 256.
// 32 pixels/block, 8 lanes per pixel; logits AND packed per-round weights in
// registers; each (o,y) 16B cell written ONCE. Output f16.
// ---------------------------------------------------------------------------
__global__ __launch_bounds__(256) void k_softmax(
        const float* __restrict__ logits, u16* __restrict__ Wkt) {
    __shared__ float s_lg[169 * 34];
    int tid = threadIdx.x;
    int y0 = blockIdx.x * 32;
    for (int idx = tid; idx < 169 * 32; idx += 256) {
        int o = idx >> 5, p = idx & 31;
        s_lg[o * 34 + p] = logits[o * HW + y0 + p];
    }
    __syncthreads();
    int pix = tid >> 3, t = tid & 7;
    int y = y0 + pix;
    float l[22];
#pragma unroll
    for (int j = 0; j < 22; j++) {
        int o = t + 8 * j;
        l[j] = (o < 169) ? s_lg[o * 34 + pix] : -3e38f;
    }
    u32 wp0[22], wp1[22], wp2[22], wp3[22];
#pragma unroll
    for (int j = 0; j < 22; j++) { wp0[j] = 0u; wp1[j] = 0u; wp2[j] = 0u; wp3[j] = 0u; }

    float e[22];
#pragma unroll
    for (int k = 0; k < 7; k++) {
        float m = -3e38f;
#pragma unroll
        for (int j = 0; j < 22; j++) m = fmaxf(m, l[j]);
        m = fmaxf(m, __shfl_xor(m, 1));
        m = fmaxf(m, __shfl_xor(m, 2));
        m = fmaxf(m, __shfl_xor(m, 4));
        float s = 0.f;
#pragma unroll
        for (int j = 0; j < 22; j++) { e[j] = __expf(l[j] - m); s += e[j]; }
        s += __shfl_xor(s, 1);
        s += __shfl_xor(s, 2);
        s += __shfl_xor(s, 4);
        float rs = 1.0f / s;
#pragma unroll
        for (int j = 0; j < 22; j++) {
            float w = e[j] * rs;
            u32 h = (u32)f2h(w);
            if (k == 0) wp0[j] |= h;
            else if (k == 1) wp0[j] |= h << 16;
            else if (k == 2) wp1[j] |= h;
            else if (k == 3) wp1[j] |= h << 16;
            else if (k == 4) wp2[j] |= h;
            else if (k == 5) wp2[j] |= h << 16;
            else wp3[j] |= h;
            if (k < 6) l[j] += __logf(fmaxf(1.0f - w, 1e-6f));
        }
    }
#pragma unroll
    for (int j = 0; j < 22; j++) {
        int o = t + 8 * j;
        if (o < 169)
            *reinterpret_cast<uint4*>(Wkt + (o * HW + y) * 8) =
                make_uint4(wp0[j], wp1[j], wp2[j], wp3[j]);
    }
}

// ---------------------------------------------------------------------------
// K2b: 7x7 boxsum of Wkt(f16) -> WsT[o][y][k8] f16. grid (169, 16 tiles 32x32).
// ---------------------------------------------------------------------------
__global__ __launch_bounds__(256) void k_wsum(
        const u16* __restrict__ Wkt, u16* __restrict__ WsT) {
    __shared__ u16 s_w[38 * 38 * 8];
    __shared__ float s_v[32 * 38 * 8];
    int o = blockIdx.x;
    int tile = blockIdx.y;
    int h0 = (tile >> 2) * 32, w0 = (tile & 3) * 32;
    int tid = threadIdx.x;

    for (int idx = tid; idx < 38 * 38; idx += 256) {
        int r = idx / 38, c = idx - r * 38;
        int gy = h0 - 3 + r, gx = w0 - 3 + c;
        uint4 v = make_uint4(0u, 0u, 0u, 0u);
        if ((unsigned)gy < 128u && (unsigned)gx < 128u)
            v = *reinterpret_cast<const uint4*>(Wkt + (o * HW + gy * 128 + gx) * 8);
        *reinterpret_cast<uint4*>(s_w + idx * 8) = v;
    }
    __syncthreads();

    if (tid < 152) {  // vertical: 38 cols x 4 groups of 8 out-rows
        int c = tid >> 2, g = tid & 3;
        int r0 = g * 8;
        float acc[7];
#pragma unroll
        for (int k = 0; k < 7; k++) acc[k] = 0.f;
#pragma unroll
        for (int d = 0; d < 7; d++) {
            uint4 q = *reinterpret_cast<const uint4*>(s_w + ((r0 + d) * 38 + c) * 8);
            acc[0] += h2f((u16)(q.x & 0xffffu)); acc[1] += h2f((u16)(q.x >> 16));
            acc[2] += h2f((u16)(q.y & 0xffffu)); acc[3] += h2f((u16)(q.y >> 16));
            acc[4] += h2f((u16)(q.z & 0xffffu)); acc[5] += h2f((u16)(q.z >> 16));
            acc[6] += h2f((u16)(q.w & 0xffffu));
        }
#pragma unroll
        for (int k = 0; k < 7; k++) s_v[(r0 * 38 + c) * 8 + k] = acc[k];
        for (int i = 1; i < 8; i++) {
            uint4 qn = *reinterpret_cast<const uint4*>(s_w + ((r0 + i + 6) * 38 + c) * 8);
            uint4 qo = *reinterpret_cast<const uint4*>(s_w + ((r0 + i - 1) * 38 + c) * 8);
            acc[0] += h2f((u16)(qn.x & 0xffffu)) - h2f((u16)(qo.x & 0xffffu));
            acc[1] += h2f((u16)(qn.x >> 16)) - h2f((u16)(qo.x >> 16));
            acc[2] += h2f((u16)(qn.y & 0xffffu)) - h2f((u16)(qo.y & 0xffffu));
            acc[3] += h2f((u16)(qn.y >> 16)) - h2f((u16)(qo.y >> 16));
            acc[4] += h2f((u16)(qn.z & 0xffffu)) - h2f((u16)(qo.z & 0xffffu));
            acc[5] += h2f((u16)(qn.z >> 16)) - h2f((u16)(qo.z >> 16));
            acc[6] += h2f((u16)(qn.w & 0xffffu)) - h2f((u16)(qo.w & 0xffffu));
#pragma unroll
            for (int k = 0; k < 7; k++) s_v[((r0 + i) * 38 + c) * 8 + k] = acc[k];
        }
    }
    __syncthreads();

    if (tid < 128) {  // horizontal: 32 rows x 4 groups of 8 out-cols
        int r = tid >> 2, g = tid & 3;
        int c0 = g * 8;
        float acc[7];
#pragma unroll
        for (int k = 0; k < 7; k++) acc[k] = 0.f;
        for (int d = 0; d < 7; d++) {
#pragma unroll
            for (int k = 0; k < 7; k++) acc[k] += s_v[(r * 38 + c0 + d) * 8 + k];
        }
        for (int i = 0; i < 8; i++) {
            if (i > 0) {
#pragma unroll
                for (int k = 0; k < 7; k++)
                    acc[k] += s_v[(r * 38 + c0 + i + 6) * 8 + k] - s_v[(r * 38 + c0 + i - 1) * 8 + k];
            }
            u32 p0 = (u32)f2h(acc[0]) | ((u32)f2h(acc[1]) << 16);
            u32 p1 = (u32)f2h(acc[2]) | ((u32)f2h(acc[3]) << 16);
            u32 p2 = (u32)f2h(acc[4]) | ((u32)f2h(acc[5]) << 16);
            u32 p3 = (u32)f2h(acc[6]);
            int y = (h0 + r) * 128 + (w0 + c0 + i);
            *reinterpret_cast<uint4*>(WsT + (o * HW + y) * 8) = make_uint4(p0, p1, p2, p3);
        }
    }
}

// ---------------------------------------------------------------------------
// K3 v4: aggregation via v_dot2_f32_f16.
// out[k,c,y] = sum_o WsT[o,y,k] * x[c, y+off(o)].
// grid 1024 = 256 tiles (4x16 pix) x 4 c-splits (16ch); 256 thr = 64 pix x 4 cc.
// x staged CHANNEL-MAJOR in LDS ([16ch][16r][32c] f16); dj paired for dot2.
// ---------------------------------------------------------------------------
#define SELLO 0x05040100u
#define SELHI 0x07060302u
__global__ __launch_bounds__(256, 4) void k_agg(
        const u16* __restrict__ xh, const u16* __restrict__ WsT,
        float* __restrict__ out) {
    __shared__ u16 s_x[16 * 16 * 32];   // [ch][r][c pad32] f16
    int tb = blockIdx.x & 255;
    int csplit = blockIdx.x >> 8;       // 16 channels per split
    int h0 = (tb >> 3) * 4, w0 = (tb & 7) * 16;
    int tid = threadIdx.x;

    for (int it = tid; it < 1024; it += 256) {
        int ch = it >> 6;
        int r = (it >> 2) & 15;
        int c0 = (it & 3) * 8;
        int gy = h0 - 6 + r, gx0 = w0 - 6 + c0;
        int gc = csplit * 16 + ch;
        uint4 v = make_uint4(0u, 0u, 0u, 0u);
        if ((unsigned)gy < 128u) {
            const u16* src = xh + (gc * 128 + gy) * 128;
            if (gx0 >= 0 && gx0 <= 120) {
                v = *reinterpret_cast<const uint4*>(src + gx0);
            } else {
                auto pk = [&](int gx) -> u32 {
                    u32 lo = ((unsigned)gx < 128u) ? (u32)src[gx] : 0u;
                    u32 hi = ((unsigned)(gx + 1) < 128u) ? (u32)src[gx + 1] : 0u;
                    return lo | (hi << 16);
                };
                v = make_uint4(pk(gx0), pk(gx0 + 2), pk(gx0 + 4), pk(gx0 + 6));
            }
        }
        *reinterpret_cast<uint4*>(s_x + (ch * 16 + r) * 32 + c0) = v;
    }
    __syncthreads();

    int cc = tid >> 6, pix = tid & 63;
    int pr = pix >> 4, pc = pix & 15;
    int y = (h0 + pr) * 128 + (w0 + pc);
    const u16* wsrc = WsT + (size_t)y * 8;
    const u32* s_x32 = reinterpret_cast<const u32*>(s_x);
    u32 sh = (u32)(pc & 1) * 16;
    int cbase_dw = (pc >> 1);

    float acc[7][4];
#pragma unroll
    for (int k = 0; k < 7; k++)
#pragma unroll
        for (int q = 0; q < 4; q++) acc[k][q] = 0.f;

#pragma unroll 1
    for (int di = 0; di < 13; di++) {
        uint4 WA[7], WB[7];
#pragma unroll
        for (int djp = 0; djp < 7; djp++) {
            int o0 = di * 13 + 2 * djp;
            WA[djp] = *reinterpret_cast<const uint4*>(wsrc + (size_t)o0 * (HW * 8));
            WB[djp] = (djp < 6)
                ? *reinterpret_cast<const uint4*>(wsrc + (size_t)(o0 + 1) * (HW * 8))
                : make_uint4(0u, 0u, 0u, 0u);
        }
        int rowb = (pr + di) * 16 + cbase_dw;
#pragma unroll
        for (int djp = 0; djp < 7; djp++) {
            u32 wp[7];
            wp[0] = __builtin_amdgcn_perm(WB[djp].x, WA[djp].x, SELLO);
            wp[1] = __builtin_amdgcn_perm(WB[djp].x, WA[djp].x, SELHI);
            wp[2] = __builtin_amdgcn_perm(WB[djp].y, WA[djp].y, SELLO);
            wp[3] = __builtin_amdgcn_perm(WB[djp].y, WA[djp].y, SELHI);
            wp[4] = __builtin_amdgcn_perm(WB[djp].z, WA[djp].z, SELLO);
            wp[5] = __builtin_amdgcn_perm(WB[djp].z, WA[djp].z, SELHI);
            wp[6] = __builtin_amdgcn_perm(WB[djp].w, WA[djp].w, SELLO);
#pragma unroll
            for (int q = 0; q < 4; q++) {
                const u32* p = s_x32 + ((cc * 4 + q) * 256 + rowb + djp);
                u32 d0 = p[0], d1 = p[1];
                u32 x2 = __builtin_amdgcn_alignbit(d1, d0, sh);
#pragma unroll
                for (int k = 0; k < 7; k++)
                    dot2acc(acc[k][q], wp[k], x2);
            }
        }
    }

    int cb = csplit * 16 + cc * 4;
#pragma unroll
    for (int k = 0; k < 7; k++)
#pragma unroll
        for (int q = 0; q < 4; q++)
            out[(k * 64 + cb + q) * HW + y] = acc[k][q];
}

// ---------------------------------------------------------------------------
extern "C" void kernel_launch(void* const* d_in, const int* in_sizes, int n_in,
                              void* d_out, int out_size, void* d_ws, size_t ws_size,
                              hipStream_t stream) {
    (void)in_sizes; (void)n_in; (void)out_size; (void)ws_size;
    const float* x  = (const float*)d_in[0];
    const float* xe = (const float*)d_in[1];
    const float* ye = (const float*)d_in[2];
    const float* lt = (const float*)d_in[3];
    float* out = (float*)d_out;
    char* ws = (char*)d_ws;

    u16*   xh     = (u16*)(ws + 0);            //  2,097,152 B (f16 [64][128][128])
    float* xeT    = (float*)(ws + 2097152u);   //  2,097,152
    float* yeT    = (float*)(ws + 4194304u);   //  2,097,152
    float* logits = (float*)(ws + 6291456u);   // 11,075,584 -> 17,367,040
    u16*   Wkt    = (u16*)(ws + 17367040u);    // 44,302,336 -> 61,669,376
    u16*   WsT    = (u16*)(ws + 61669376u);    // 44,302,336 -> 105,971,712
    // nx/ny/st live in Wkt's first 256KB: dead once k_softmax writes Wkt,
    // and k_logits (their last reader) runs before k_softmax.
    float*  nx = (float*)(ws + 17367040u);            // 65,536
    float*  ny = (float*)(ws + 17367040u + 65536u);   // 65,536
    float2* st = (float2*)(ws + 17367040u + 131072u); // 131,072

    k_prep<<<64, 256, 0, stream>>>(x, xe, ye, xh, xeT, yeT, nx, ny);
    k_norms<<<64, 256, 0, stream>>>(ny, lt, st);
    k_logits<<<dim3(13, 64), 1024, 0, stream>>>(xeT, yeT, nx, st, logits);
    k_softmax<<<512, 256, 0, stream>>>(logits, Wkt);
    k_wsum<<<dim3(169, 16), 256, 0, stream>>>(Wkt, WsT);
    k_agg<<<1024, 256, 0, stream>>>(xh, WsT, out);
}

// Round 6
// 175.578 us; speedup vs baseline: 1.1567x; 1.0316x over previous
//
#include <hip/hip_runtime.h>
#include <hip/hip_bf16.h>
#include <hip/hip_fp16.h>

// N3 aggregation: C=64, E=32, H=W=128, K=7, PS=7 (PR=3), WS=13 (WR=6), O=169
#define HW 16384

using u16 = unsigned short;
using u32 = unsigned int;
typedef __attribute__((ext_vector_type(2))) float f32x2;

__device__ __forceinline__ u16 f2h(float f) {
    __half h = __float2half(f);
    return __builtin_bit_cast(u16, h);
}
// acc += a.x*b.x + a.y*b.y  (f16 pairs, f32 accumulate)
__device__ __forceinline__ void dot2acc(float& acc, u32 a, u32 b) {
    asm("v_dot2_f32_f16 %0, %1, %2, %0" : "+v"(acc) : "v"(a), "v"(b));
}
#define SELLO 0x05040100u
#define SELHI 0x07060302u

// ---------------------------------------------------------------------------
// K0: transposes + per-pixel norms. grid 64 x 256. one thread per pixel.
// ---------------------------------------------------------------------------
__global__ __launch_bounds__(256) void k_prep(
        const float* __restrict__ x, const float* __restrict__ xe,
        const float* __restrict__ ye,
        u16* __restrict__ xh, float* __restrict__ xeT,
        float* __restrict__ yeT, float* __restrict__ nx, float* __restrict__ ny) {
    int y = blockIdx.x * 256 + threadIdx.x;

#pragma unroll
    for (int c = 0; c < 64; c++)
        xh[c * HW + y] = f2h(x[c * HW + y]);

    float sx = 0.f, sy = 0.f;
#pragma unroll
    for (int e0 = 0; e0 < 32; e0 += 4) {
        float4 v = make_float4(xe[(e0 + 0) * HW + y], xe[(e0 + 1) * HW + y],
                               xe[(e0 + 2) * HW + y], xe[(e0 + 3) * HW + y]);
        *reinterpret_cast<float4*>(xeT + y * 32 + e0) = v;
        sx += v.x * v.x + v.y * v.y + v.z * v.z + v.w * v.w;
        float4 u = make_float4(ye[(e0 + 0) * HW + y], ye[(e0 + 1) * HW + y],
                               ye[(e0 + 2) * HW + y], ye[(e0 + 3) * HW + y]);
        *reinterpret_cast<float4*>(yeT + y * 32 + e0) = u;
        sy += u.x * u.x + u.y * u.y + u.z * u.z + u.w * u.w;
    }
    nx[y] = sx;
    ny[y] = sy;
}

// ---------------------------------------------------------------------------
// K0b: st[y] = (tinv, tinv*Sy), tinv = exp(-boxsum(lt)/49), Sy = boxsum(ny).
// ---------------------------------------------------------------------------
__global__ __launch_bounds__(256) void k_norms(
        const float* __restrict__ ny, const float* __restrict__ lt,
        float2* __restrict__ st) {
    int y = blockIdx.x * 256 + threadIdx.x;
    int py = y >> 7, px = y & 127;
    float s = 0.f, t = 0.f;
    for (int dy = -3; dy <= 3; dy++)
        for (int dx = -3; dx <= 3; dx++) {
            int yy = py + dy, xx = px + dx;
            if ((unsigned)yy < 128u && (unsigned)xx < 128u) {
                int p = yy * 128 + xx;
                s += ny[p];
                t += lt[p];
            }
        }
    float tinv = __expf(-t * (1.0f / 49.0f));
    st[y] = make_float2(tinv, tinv * s);
}

// ---------------------------------------------------------------------------
// K1 v2: logits[o][y] = -tinv*( Sy(y) + boxsum_z( nx(z+o) - 2*ye(z).xe(z+o) ) ).
// grid (13 di, 64 tiles of 16x16), 1024 threads. (unchanged from round 4)
// ---------------------------------------------------------------------------
__global__ __launch_bounds__(1024) void k_logits(
        const float* __restrict__ xeT, const float* __restrict__ yeT,
        const float* __restrict__ nxg, const float2* __restrict__ st,
        float* __restrict__ logits) {
#pragma clang fp contract(fast)
    __shared__ __align__(16) char arena[123904];
    float* s_xe = (float*)arena;              // 748 cells * 32 dw, swizzled
    float* s_nx = (float*)(arena + 95744);    // 748
    float* s_d2 = (float*)(arena + 98736);    // 13 * 484
    float* s_hs = (float*)arena;              // overlay after compute: 13*22*16

    int di = blockIdx.x;
    int tile = blockIdx.y;
    int h0 = (tile >> 3) * 16, w0 = (tile & 7) * 16;
    int gr0 = h0 + di - 9, gc0 = w0 - 9;
    int tid = threadIdx.x;

    for (int idx = tid; idx < 748 * 8; idx += 1024) {
        int cell = idx >> 3, q = idx & 7;
        int r = cell / 34, c = cell - r * 34;
        int gy = gr0 + r, gx = gc0 + c;
        float4 v = make_float4(0.f, 0.f, 0.f, 0.f);
        if ((unsigned)gy < 128u && (unsigned)gx < 128u)
            v = *reinterpret_cast<const float4*>(xeT + (size_t)(gy * 128 + gx) * 32 + q * 4);
        *reinterpret_cast<float4*>(s_xe + cell * 32 + ((q ^ (cell & 7)) << 2)) = v;
    }
    for (int idx = tid; idx < 748; idx += 1024) {
        int r = idx / 34, c = idx - r * 34;
        int gy = gr0 + r, gx = gc0 + c;
        float v = 0.f;
        if ((unsigned)gy < 128u && (unsigned)gx < 128u) v = nxg[gy * 128 + gx];
        s_nx[idx] = v;
    }
    __syncthreads();

    if (tid < 484) {
        int zr = tid / 22, zc = tid - zr * 22;
        int gy = h0 - 3 + zr, gx = w0 - 3 + zc;
        bool zin = ((unsigned)gy < 128u) && ((unsigned)gx < 128u);
        f32x2 yv[16];
#pragma unroll
        for (int j = 0; j < 16; j++) yv[j] = (f32x2){0.f, 0.f};
        if (zin) {
            const float* yp = yeT + (size_t)(gy * 128 + gx) * 32;
#pragma unroll
            for (int j = 0; j < 8; j++) {
                float4 t = *reinterpret_cast<const float4*>(yp + j * 4);
                yv[2 * j] = (f32x2){t.x, t.y};
                yv[2 * j + 1] = (f32x2){t.z, t.w};
            }
        }
        int cell0 = zr * 34 + zc;
#pragma unroll
        for (int dj = 0; dj < 13; dj++) {
            int cell = cell0 + dj;
            const float* bp = s_xe + cell * 32;
            int sw = cell & 7;
            f32x2 a0 = {0.f, 0.f}, a1 = {0.f, 0.f};
#pragma unroll
            for (int q = 0; q < 8; q++) {
                float4 xv = *reinterpret_cast<const float4*>(bp + ((q ^ sw) << 2));
                a0 += ((f32x2){xv.x, xv.y}) * yv[2 * q];
                a1 += ((f32x2){xv.z, xv.w}) * yv[2 * q + 1];
            }
            float cr = a0.x + a0.y + a1.x + a1.y;
            float d2v = fmaf(-2.f, cr, s_nx[cell]);
            s_d2[dj * 484 + tid] = zin ? d2v : 0.f;
        }
    }
    __syncthreads();

    for (int idx = tid; idx < 4576; idx += 1024) {
        int dj = idx / 352, rem = idx - dj * 352;
        int r = rem >> 4, c = rem & 15;
        const float* p = s_d2 + dj * 484 + r * 22 + c;
        float s = p[0] + p[1] + p[2] + p[3] + p[4] + p[5] + p[6];
        s_hs[(dj * 22 + r) * 16 + c] = s;
    }
    __syncthreads();

    for (int idx = tid; idx < 3328; idx += 1024) {
        int dj = idx >> 8, rem = idx & 255;
        int i = rem >> 4, jj = rem & 15;
        const float* p = s_hs + (dj * 22 + i) * 16 + jj;
        float s = p[0] + p[16] + p[32] + p[48] + p[64] + p[80] + p[96];
        int y = (h0 + i) * 128 + (w0 + jj);
        float2 ab = st[y];
        logits[(di * 13 + dj) * HW + y] = -fmaf(ab.x, s, ab.y);
    }
}

// ---------------------------------------------------------------------------
// K2: K=7 rounds of exclusion softmax over O=169. grid 512 x 256. (unchanged)
// ---------------------------------------------------------------------------
__global__ __launch_bounds__(256) void k_softmax(
        const float* __restrict__ logits, u16* __restrict__ Wkt) {
    __shared__ float s_lg[169 * 34];
    int tid = threadIdx.x;
    int y0 = blockIdx.x * 32;
    for (int idx = tid; idx < 169 * 32; idx += 256) {
        int o = idx >> 5, p = idx & 31;
        s_lg[o * 34 + p] = logits[o * HW + y0 + p];
    }
    __syncthreads();
    int pix = tid >> 3, t = tid & 7;
    int y = y0 + pix;
    float l[22];
#pragma unroll
    for (int j = 0; j < 22; j++) {
        int o = t + 8 * j;
        l[j] = (o < 169) ? s_lg[o * 34 + pix] : -3e38f;
    }
    u32 wp0[22], wp1[22], wp2[22], wp3[22];
#pragma unroll
    for (int j = 0; j < 22; j++) { wp0[j] = 0u; wp1[j] = 0u; wp2[j] = 0u; wp3[j] = 0u; }

    float e[22];
#pragma unroll
    for (int k = 0; k < 7; k++) {
        float m = -3e38f;
#pragma unroll
        for (int j = 0; j < 22; j++) m = fmaxf(m, l[j]);
        m = fmaxf(m, __shfl_xor(m, 1));
        m = fmaxf(m, __shfl_xor(m, 2));
        m = fmaxf(m, __shfl_xor(m, 4));
        float s = 0.f;
#pragma unroll
        for (int j = 0; j < 22; j++) { e[j] = __expf(l[j] - m); s += e[j]; }
        s += __shfl_xor(s, 1);
        s += __shfl_xor(s, 2);
        s += __shfl_xor(s, 4);
        float rs = 1.0f / s;
#pragma unroll
        for (int j = 0; j < 22; j++) {
            float w = e[j] * rs;
            u32 h = (u32)f2h(w);
            if (k == 0) wp0[j] |= h;
            else if (k == 1) wp0[j] |= h << 16;
            else if (k == 2) wp1[j] |= h;
            else if (k == 3) wp1[j] |= h << 16;
            else if (k == 4) wp2[j] |= h;
            else if (k == 5) wp2[j] |= h << 16;
            else wp3[j] |= h;
            if (k < 6) l[j] += __logf(fmaxf(1.0f - w, 1e-6f));
        }
    }
#pragma unroll
    for (int j = 0; j < 22; j++) {
        int o = t + 8 * j;
        if (o < 169)
            *reinterpret_cast<uint4*>(Wkt + (o * HW + y) * 8) =
                make_uint4(wp0[j], wp1[j], wp2[j], wp3[j]);
    }
}

// ---------------------------------------------------------------------------
// K2b v2: 7x7 boxsum of Wkt(f16) -> PAIR-PACKED WsP[o2][y][8 u32],
// u32[k] = (f16 w(di,2djp,k) , f16 w(di,2djp+1,k)); slot 7 = 0.
// grid (91 = 13di x 7djp, 16 tiles of 32x32), 256 thr, all-thread phases,
// v_pk_add_f16 taps, f16 s_v, register-carry of pass-A across pass-B.
// ---------------------------------------------------------------------------
__global__ __launch_bounds__(256) void k_wsum(
        const u16* __restrict__ Wkt, u32* __restrict__ WsP) {
    __shared__ u16 s_w[38 * 39 * 8];   // [row][col pad39][k8]
    __shared__ u16 s_v[32 * 38 * 8];   // [outrow][col][k8] f16 vertical sums
    int o2 = blockIdx.x;
    int di = o2 / 7, djp = o2 - di * 7;
    int oA = di * 13 + 2 * djp;
    bool hasB = (djp < 6);
    int tile = blockIdx.y;
    int h0 = (tile >> 2) * 32, w0 = (tile & 3) * 32;
    int tid = threadIdx.x;

    auto stage = [&](int o) {
        const u16* src = Wkt + (size_t)o * (HW * 8);
        for (int idx = tid; idx < 38 * 38; idx += 256) {
            int r = idx / 38, c = idx - r * 38;
            int gy = h0 - 3 + r, gx = w0 - 3 + c;
            uint4 v = make_uint4(0u, 0u, 0u, 0u);
            if ((unsigned)gy < 128u && (unsigned)gx < 128u)
                v = *reinterpret_cast<const uint4*>(src + (gy * 128 + gx) * 8);
            *reinterpret_cast<uint4*>(s_w + (r * 39 + c) * 8) = v;
        }
    };
    auto vert = [&]() {
        for (int u = tid; u < 1216; u += 256) {   // 32 out-rows x 38 cols
            int r = u / 38, c = u - r * 38;
            __half2 s0 = __builtin_bit_cast(__half2, 0u);
            __half2 s1 = s0, s2 = s0, s3 = s0;
#pragma unroll
            for (int d = 0; d < 7; d++) {
                uint4 q = *reinterpret_cast<const uint4*>(s_w + ((r + d) * 39 + c) * 8);
                s0 = __hadd2(s0, __builtin_bit_cast(__half2, q.x));
                s1 = __hadd2(s1, __builtin_bit_cast(__half2, q.y));
                s2 = __hadd2(s2, __builtin_bit_cast(__half2, q.z));
                s3 = __hadd2(s3, __builtin_bit_cast(__half2, q.w));
            }
            *reinterpret_cast<uint4*>(s_v + (r * 38 + c) * 8) = make_uint4(
                __builtin_bit_cast(u32, s0), __builtin_bit_cast(u32, s1),
                __builtin_bit_cast(u32, s2), __builtin_bit_cast(u32, s3));
        }
    };
    auto horiz = [&](uint4 (&rr)[4]) {
#pragma unroll
        for (int i = 0; i < 4; i++) {              // 32 rows x 32 out-cols
            int u = tid + i * 256;
            int r = u >> 5, cx = u & 31;
            __half2 s0 = __builtin_bit_cast(__half2, 0u);
            __half2 s1 = s0, s2 = s0, s3 = s0;
#pragma unroll
            for (int d = 0; d < 7; d++) {
                uint4 q = *reinterpret_cast<const uint4*>(s_v + (r * 38 + cx + d) * 8);
                s0 = __hadd2(s0, __builtin_bit_cast(__half2, q.x));
                s1 = __hadd2(s1, __builtin_bit_cast(__half2, q.y));
                s2 = __hadd2(s2, __builtin_bit_cast(__half2, q.z));
                s3 = __hadd2(s3, __builtin_bit_cast(__half2, q.w));
            }
            rr[i] = make_uint4(
                __builtin_bit_cast(u32, s0), __builtin_bit_cast(u32, s1),
                __builtin_bit_cast(u32, s2), __builtin_bit_cast(u32, s3));
        }
    };

    uint4 rA[4], rB[4];
#pragma unroll
    for (int i = 0; i < 4; i++) rB[i] = make_uint4(0u, 0u, 0u, 0u);

    stage(oA);
    __syncthreads();
    vert();
    __syncthreads();
    horiz(rA);
    if (hasB) {
        __syncthreads();           // rA-horiz reads done; safe to overwrite s_w
        stage(oA + 1);
        __syncthreads();
        vert();
        __syncthreads();
        horiz(rB);
    }

#pragma unroll
    for (int i = 0; i < 4; i++) {
        int u = tid + i * 256;
        int r = u >> 5, cx = u & 31;
        int y = (h0 + r) * 128 + (w0 + cx);
        u32* dst = WsP + ((size_t)o2 * HW + y) * 8;
        uint4 lo = make_uint4(
            __builtin_amdgcn_perm(rB[i].x, rA[i].x, SELLO),
            __builtin_amdgcn_perm(rB[i].x, rA[i].x, SELHI),
            __builtin_amdgcn_perm(rB[i].y, rA[i].y, SELLO),
            __builtin_amdgcn_perm(rB[i].y, rA[i].y, SELHI));
        uint4 hi = make_uint4(
            __builtin_amdgcn_perm(rB[i].z, rA[i].z, SELLO),
            __builtin_amdgcn_perm(rB[i].z, rA[i].z, SELHI),
            __builtin_amdgcn_perm(rB[i].w, rA[i].w, SELLO),
            0u);
        *reinterpret_cast<uint4*>(dst) = lo;
        *reinterpret_cast<uint4*>(dst + 4) = hi;
    }
}

// ---------------------------------------------------------------------------
// K3 v5: aggregation, perm-free via pair-packed WsP.
// out[k,c,y] = sum_o WsP-pair dot x-pair.
// grid 2048 = 512 tiles (4x8 pix) x 4 c-splits (16ch); 256 thr = 32 pix x 8 cc(2ch).
// s_x [16ch][16r][24c] f16 (halo w0-8..w0+15); per (di,djp,ch):
// ds_read2_b32 + alignbit + 7 dot2 with directly-loaded wp[0..6].
// ---------------------------------------------------------------------------
__global__ __launch_bounds__(256, 6) void k_agg(
        const u16* __restrict__ xh, const u32* __restrict__ WsP,
        float* __restrict__ out) {
    __shared__ u16 s_x[16 * 16 * 24];   // [ch][r][c] f16
    int tb = blockIdx.x & 511;
    int csplit = blockIdx.x >> 9;       // 16 channels per split
    int h0 = (tb >> 4) * 4, w0 = (tb & 15) * 8;
    int tid = threadIdx.x;

    // stage: 768 units = 16ch x 16r x 3 chunks of 8 cols
#pragma unroll
    for (int i = 0; i < 3; i++) {
        int it = tid + i * 256;
        int ch = it / 48, rem = it - ch * 48;
        int r = rem / 3, j = rem - r * 3;
        int gy = h0 - 6 + r, gx0 = w0 - 8 + 8 * j;
        int gc = csplit * 16 + ch;
        uint4 v = make_uint4(0u, 0u, 0u, 0u);
        if ((unsigned)gy < 128u) {
            const u16* src = xh + (size_t)gc * HW + gy * 128;
            if (gx0 >= 0 && gx0 + 7 < 128) {
                v = *reinterpret_cast<const uint4*>(src + gx0);
            } else {
                auto pk = [&](int gx) -> u32 {
                    u32 lo = ((unsigned)gx < 128u) ? (u32)src[gx] : 0u;
                    u32 hi = ((unsigned)(gx + 1) < 128u) ? (u32)src[gx + 1] : 0u;
                    return lo | (hi << 16);
                };
                v = make_uint4(pk(gx0), pk(gx0 + 2), pk(gx0 + 4), pk(gx0 + 6));
            }
        }
        *reinterpret_cast<uint4*>(s_x + (ch * 16 + r) * 24 + 8 * j) = v;
    }
    __syncthreads();

    int cc = tid >> 5, pix = tid & 31;
    int pr = pix >> 3, pc = pix & 7;
    int y = (h0 + pr) * 128 + (w0 + pc);
    const u32* wsrc = WsP + (size_t)y * 8;
    const u32* s_x32 = reinterpret_cast<const u32*>(s_x);
    u32 sh = (u32)(pc & 1) * 16;
    int xbase = cc * 2 * 192 + pr * 12 + ((pc + 2) >> 1);  // dword index

    float acc[7][2];
#pragma unroll
    for (int k = 0; k < 7; k++) { acc[k][0] = 0.f; acc[k][1] = 0.f; }

#pragma unroll 1
    for (int di = 0; di < 13; di++) {
        const u32* xp = s_x32 + xbase + di * 12;
        const u32* wdi = wsrc + (size_t)(di * 7) * (HW * 8);
#pragma unroll
        for (int djp = 0; djp < 7; djp++) {
            const u32* wp = wdi + (size_t)djp * (HW * 8);
            uint4 W0 = *reinterpret_cast<const uint4*>(wp);
            uint4 W1 = *reinterpret_cast<const uint4*>(wp + 4);
            {   // q = 0 (ch = cc*2)
                u32 d0 = xp[djp], d1 = xp[djp + 1];
                u32 x2 = __builtin_amdgcn_alignbit(d1, d0, sh);
                dot2acc(acc[0][0], W0.x, x2); dot2acc(acc[1][0], W0.y, x2);
                dot2acc(acc[2][0], W0.z, x2); dot2acc(acc[3][0], W0.w, x2);
                dot2acc(acc[4][0], W1.x, x2); dot2acc(acc[5][0], W1.y, x2);
                dot2acc(acc[6][0], W1.z, x2);
            }
            {   // q = 1 (ch = cc*2+1)
                u32 d0 = xp[192 + djp], d1 = xp[192 + djp + 1];
                u32 x2 = __builtin_amdgcn_alignbit(d1, d0, sh);
                dot2acc(acc[0][1], W0.x, x2); dot2acc(acc[1][1], W0.y, x2);
                dot2acc(acc[2][1], W0.z, x2); dot2acc(acc[3][1], W0.w, x2);
                dot2acc(acc[4][1], W1.x, x2); dot2acc(acc[5][1], W1.y, x2);
                dot2acc(acc[6][1], W1.z, x2);
            }
        }
    }

    int cb = csplit * 16 + cc * 2;
#pragma unroll
    for (int k = 0; k < 7; k++) {
        out[(k * 64 + cb + 0) * HW + y] = acc[k][0];
        out[(k * 64 + cb + 1) * HW + y] = acc[k][1];
    }
}

// ---------------------------------------------------------------------------
extern "C" void kernel_launch(void* const* d_in, const int* in_sizes, int n_in,
                              void* d_out, int out_size, void* d_ws, size_t ws_size,
                              hipStream_t stream) {
    (void)in_sizes; (void)n_in; (void)out_size; (void)ws_size;
    const float* x  = (const float*)d_in[0];
    const float* xe = (const float*)d_in[1];
    const float* ye = (const float*)d_in[2];
    const float* lt = (const float*)d_in[3];
    float* out = (float*)d_out;
    char* ws = (char*)d_ws;

    // layout (98.3 MB total):
    u16*   xh     = (u16*)(ws + 0);            //  2,097,152 B (f16 [64][128][128])
    float* xeT    = (float*)(ws + 2097152u);   //  2,097,152
    float* yeT    = (float*)(ws + 4194304u);   //  2,097,152
    u16*   Wkt    = (u16*)(ws + 6291456u);     // 44,302,336 -> 50,593,792
    float* logits = (float*)(ws + 50593792u);  // 11,075,584 (dead after k_softmax)
    u32*   WsP    = (u32*)(ws + 50593792u);    // 47,710,208 -> 98,304,000 (overlays logits)
    // nx/ny/st overlay Wkt head: written by k_prep/k_norms, last read by
    // k_logits; Wkt is written later by k_softmax.
    float*  nx = (float*)(ws + 6291456u);             // 65,536
    float*  ny = (float*)(ws + 6291456u + 65536u);    // 65,536
    float2* st = (float2*)(ws + 6291456u + 131072u);  // 131,072

    k_prep<<<64, 256, 0, stream>>>(x, xe, ye, xh, xeT, yeT, nx, ny);
    k_norms<<<64, 256, 0, stream>>>(ny, lt, st);
    k_logits<<<dim3(13, 64), 1024, 0, stream>>>(xeT, yeT, nx, st, logits);
    k_softmax<<<512, 256, 0, stream>>>(logits, Wkt);
    k_wsum<<<dim3(91, 16), 256, 0, stream>>>(Wkt, WsP);
    k_agg<<<2048, 256, 0, stream>>>(xh, WsP, out);
}

// Round 7
// 157.000 us; speedup vs baseline: 1.2936x; 1.1183x over previous
//
#include <hip/hip_runtime.h>
#include <hip/hip_bf16.h>
#include <hip/hip_fp16.h>

// N3 aggregation: C=64, E=32, H=W=128, K=7, PS=7 (PR=3), WS=13 (WR=6), O=169
#define HW 16384

using u16 = unsigned short;
using u32 = unsigned int;
typedef __attribute__((ext_vector_type(2))) float f32x2;

__device__ __forceinline__ u16 f2h(float f) {
    __half h = __float2half(f);
    return __builtin_bit_cast(u16, h);
}
// acc += a.x*b.x + a.y*b.y  (f16 pairs, f32 accumulate)
__device__ __forceinline__ void dot2acc(float& acc, u32 a, u32 b) {
    asm("v_dot2_f32_f16 %0, %1, %2, %0" : "+v"(acc) : "v"(a), "v"(b));
}
#define SELLO 0x05040100u
#define SELHI 0x07060302u

// ---------------------------------------------------------------------------
// K0: transposes + per-pixel norms. grid 64 x 256. one thread per pixel.
// ---------------------------------------------------------------------------
__global__ __launch_bounds__(256) void k_prep(
        const float* __restrict__ x, const float* __restrict__ xe,
        const float* __restrict__ ye,
        u16* __restrict__ xh, float* __restrict__ xeT,
        float* __restrict__ yeT, float* __restrict__ nx, float* __restrict__ ny) {
    int y = blockIdx.x * 256 + threadIdx.x;

#pragma unroll
    for (int c = 0; c < 64; c++)
        xh[c * HW + y] = f2h(x[c * HW + y]);

    float sx = 0.f, sy = 0.f;
#pragma unroll
    for (int e0 = 0; e0 < 32; e0 += 4) {
        float4 v = make_float4(xe[(e0 + 0) * HW + y], xe[(e0 + 1) * HW + y],
                               xe[(e0 + 2) * HW + y], xe[(e0 + 3) * HW + y]);
        *reinterpret_cast<float4*>(xeT + y * 32 + e0) = v;
        sx += v.x * v.x + v.y * v.y + v.z * v.z + v.w * v.w;
        float4 u = make_float4(ye[(e0 + 0) * HW + y], ye[(e0 + 1) * HW + y],
                               ye[(e0 + 2) * HW + y], ye[(e0 + 3) * HW + y]);
        *reinterpret_cast<float4*>(yeT + y * 32 + e0) = u;
        sy += u.x * u.x + u.y * u.y + u.z * u.z + u.w * u.w;
    }
    nx[y] = sx;
    ny[y] = sy;
}

// ---------------------------------------------------------------------------
// K0b: st[y] = (tinv, tinv*Sy), tinv = exp(-boxsum(lt)/49), Sy = boxsum(ny).
// ---------------------------------------------------------------------------
__global__ __launch_bounds__(256) void k_norms(
        const float* __restrict__ ny, const float* __restrict__ lt,
        float2* __restrict__ st) {
    int y = blockIdx.x * 256 + threadIdx.x;
    int py = y >> 7, px = y & 127;
    float s = 0.f, t = 0.f;
    for (int dy = -3; dy <= 3; dy++)
        for (int dx = -3; dx <= 3; dx++) {
            int yy = py + dy, xx = px + dx;
            if ((unsigned)yy < 128u && (unsigned)xx < 128u) {
                int p = yy * 128 + xx;
                s += ny[p];
                t += lt[p];
            }
        }
    float tinv = __expf(-t * (1.0f / 49.0f));
    st[y] = make_float2(tinv, tinv * s);
}

// ---------------------------------------------------------------------------
// K1 v2: logits[o][y] = -tinv*( Sy(y) + boxsum_z( nx(z+o) - 2*ye(z).xe(z+o) ) ).
// grid (13 di, 64 tiles of 16x16), 1024 threads. (unchanged)
// ---------------------------------------------------------------------------
__global__ __launch_bounds__(1024) void k_logits(
        const float* __restrict__ xeT, const float* __restrict__ yeT,
        const float* __restrict__ nxg, const float2* __restrict__ st,
        float* __restrict__ logits) {
#pragma clang fp contract(fast)
    __shared__ __align__(16) char arena[123904];
    float* s_xe = (float*)arena;              // 748 cells * 32 dw, swizzled
    float* s_nx = (float*)(arena + 95744);    // 748
    float* s_d2 = (float*)(arena + 98736);    // 13 * 484
    float* s_hs = (float*)arena;              // overlay after compute: 13*22*16

    int di = blockIdx.x;
    int tile = blockIdx.y;
    int h0 = (tile >> 3) * 16, w0 = (tile & 7) * 16;
    int gr0 = h0 + di - 9, gc0 = w0 - 9;
    int tid = threadIdx.x;

    for (int idx = tid; idx < 748 * 8; idx += 1024) {
        int cell = idx >> 3, q = idx & 7;
        int r = cell / 34, c = cell - r * 34;
        int gy = gr0 + r, gx = gc0 + c;
        float4 v = make_float4(0.f, 0.f, 0.f, 0.f);
        if ((unsigned)gy < 128u && (unsigned)gx < 128u)
            v = *reinterpret_cast<const float4*>(xeT + (size_t)(gy * 128 + gx) * 32 + q * 4);
        *reinterpret_cast<float4*>(s_xe + cell * 32 + ((q ^ (cell & 7)) << 2)) = v;
    }
    for (int idx = tid; idx < 748; idx += 1024) {
        int r = idx / 34, c = idx - r * 34;
        int gy = gr0 + r, gx = gc0 + c;
        float v = 0.f;
        if ((unsigned)gy < 128u && (unsigned)gx < 128u) v = nxg[gy * 128 + gx];
        s_nx[idx] = v;
    }
    __syncthreads();

    if (tid < 484) {
        int zr = tid / 22, zc = tid - zr * 22;
        int gy = h0 - 3 + zr, gx = w0 - 3 + zc;
        bool zin = ((unsigned)gy < 128u) && ((unsigned)gx < 128u);
        f32x2 yv[16];
#pragma unroll
        for (int j = 0; j < 16; j++) yv[j] = (f32x2){0.f, 0.f};
        if (zin) {
            const float* yp = yeT + (size_t)(gy * 128 + gx) * 32;
#pragma unroll
            for (int j = 0; j < 8; j++) {
                float4 t = *reinterpret_cast<const float4*>(yp + j * 4);
                yv[2 * j] = (f32x2){t.x, t.y};
                yv[2 * j + 1] = (f32x2){t.z, t.w};
            }
        }
        int cell0 = zr * 34 + zc;
#pragma unroll
        for (int dj = 0; dj < 13; dj++) {
            int cell = cell0 + dj;
            const float* bp = s_xe + cell * 32;
            int sw = cell & 7;
            f32x2 a0 = {0.f, 0.f}, a1 = {0.f, 0.f};
#pragma unroll
            for (int q = 0; q < 8; q++) {
                float4 xv = *reinterpret_cast<const float4*>(bp + ((q ^ sw) << 2));
                a0 += ((f32x2){xv.x, xv.y}) * yv[2 * q];
                a1 += ((f32x2){xv.z, xv.w}) * yv[2 * q + 1];
            }
            float cr = a0.x + a0.y + a1.x + a1.y;
            float d2v = fmaf(-2.f, cr, s_nx[cell]);
            s_d2[dj * 484 + tid] = zin ? d2v : 0.f;
        }
    }
    __syncthreads();

    for (int idx = tid; idx < 4576; idx += 1024) {
        int dj = idx / 352, rem = idx - dj * 352;
        int r = rem >> 4, c = rem & 15;
        const float* p = s_d2 + dj * 484 + r * 22 + c;
        float s = p[0] + p[1] + p[2] + p[3] + p[4] + p[5] + p[6];
        s_hs[(dj * 22 + r) * 16 + c] = s;
    }
    __syncthreads();

    for (int idx = tid; idx < 3328; idx += 1024) {
        int dj = idx >> 8, rem = idx & 255;
        int i = rem >> 4, jj = rem & 15;
        const float* p = s_hs + (dj * 22 + i) * 16 + jj;
        float s = p[0] + p[16] + p[32] + p[48] + p[64] + p[80] + p[96];
        int y = (h0 + i) * 128 + (w0 + jj);
        float2 ab = st[y];
        logits[(di * 13 + dj) * HW + y] = -fmaf(ab.x, s, ab.y);
    }
}

// ---------------------------------------------------------------------------
// K2: K=7 rounds of exclusion softmax over O=169. grid 512 x 256. (unchanged)
// ---------------------------------------------------------------------------
__global__ __launch_bounds__(256) void k_softmax(
        const float* __restrict__ logits, u16* __restrict__ Wkt) {
    __shared__ float s_lg[169 * 34];
    int tid = threadIdx.x;
    int y0 = blockIdx.x * 32;
    for (int idx = tid; idx < 169 * 32; idx += 256) {
        int o = idx >> 5, p = idx & 31;
        s_lg[o * 34 + p] = logits[o * HW + y0 + p];
    }
    __syncthreads();
    int pix = tid >> 3, t = tid & 7;
    int y = y0 + pix;
    float l[22];
#pragma unroll
    for (int j = 0; j < 22; j++) {
        int o = t + 8 * j;
        l[j] = (o < 169) ? s_lg[o * 34 + pix] : -3e38f;
    }
    u32 wp0[22], wp1[22], wp2[22], wp3[22];
#pragma unroll
    for (int j = 0; j < 22; j++) { wp0[j] = 0u; wp1[j] = 0u; wp2[j] = 0u; wp3[j] = 0u; }

    float e[22];
#pragma unroll
    for (int k = 0; k < 7; k++) {
        float m = -3e38f;
#pragma unroll
        for (int j = 0; j < 22; j++) m = fmaxf(m, l[j]);
        m = fmaxf(m, __shfl_xor(m, 1));
        m = fmaxf(m, __shfl_xor(m, 2));
        m = fmaxf(m, __shfl_xor(m, 4));
        float s = 0.f;
#pragma unroll
        for (int j = 0; j < 22; j++) { e[j] = __expf(l[j] - m); s += e[j]; }
        s += __shfl_xor(s, 1);
        s += __shfl_xor(s, 2);
        s += __shfl_xor(s, 4);
        float rs = 1.0f / s;
#pragma unroll
        for (int j = 0; j < 22; j++) {
            float w = e[j] * rs;
            u32 h = (u32)f2h(w);
            if (k == 0) wp0[j] |= h;
            else if (k == 1) wp0[j] |= h << 16;
            else if (k == 2) wp1[j] |= h;
            else if (k == 3) wp1[j] |= h << 16;
            else if (k == 4) wp2[j] |= h;
            else if (k == 5) wp2[j] |= h << 16;
            else wp3[j] |= h;
            if (k < 6) l[j] += __logf(fmaxf(1.0f - w, 1e-6f));
        }
    }
#pragma unroll
    for (int j = 0; j < 22; j++) {
        int o = t + 8 * j;
        if (o < 169)
            *reinterpret_cast<uint4*>(Wkt + (o * HW + y) * 8) =
                make_uint4(wp0[j], wp1[j], wp2[j], wp3[j]);
    }
}

// ---------------------------------------------------------------------------
// K2b v2: 7x7 boxsum of Wkt(f16) -> PAIR-PACKED WsP[o2][y][8 u32],
// u32[k] = (f16 w(di,2djp,k) , f16 w(di,2djp+1,k)); slot 7 = 0. (unchanged)
// ---------------------------------------------------------------------------
__global__ __launch_bounds__(256) void k_wsum(
        const u16* __restrict__ Wkt, u32* __restrict__ WsP) {
    __shared__ u16 s_w[38 * 39 * 8];   // [row][col pad39][k8]
    __shared__ u16 s_v[32 * 38 * 8];   // [outrow][col][k8] f16 vertical sums
    int o2 = blockIdx.x;
    int di = o2 / 7, djp = o2 - di * 7;
    int oA = di * 13 + 2 * djp;
    bool hasB = (djp < 6);
    int tile = blockIdx.y;
    int h0 = (tile >> 2) * 32, w0 = (tile & 3) * 32;
    int tid = threadIdx.x;

    auto stage = [&](int o) {
        const u16* src = Wkt + (size_t)o * (HW * 8);
        for (int idx = tid; idx < 38 * 38; idx += 256) {
            int r = idx / 38, c = idx - r * 38;
            int gy = h0 - 3 + r, gx = w0 - 3 + c;
            uint4 v = make_uint4(0u, 0u, 0u, 0u);
            if ((unsigned)gy < 128u && (unsigned)gx < 128u)
                v = *reinterpret_cast<const uint4*>(src + (gy * 128 + gx) * 8);
            *reinterpret_cast<uint4*>(s_w + (r * 39 + c) * 8) = v;
        }
    };
    auto vert = [&]() {
        for (int u = tid; u < 1216; u += 256) {   // 32 out-rows x 38 cols
            int r = u / 38, c = u - r * 38;
            __half2 s0 = __builtin_bit_cast(__half2, 0u);
            __half2 s1 = s0, s2 = s0, s3 = s0;
#pragma unroll
            for (int d = 0; d < 7; d++) {
                uint4 q = *reinterpret_cast<const uint4*>(s_w + ((r + d) * 39 + c) * 8);
                s0 = __hadd2(s0, __builtin_bit_cast(__half2, q.x));
                s1 = __hadd2(s1, __builtin_bit_cast(__half2, q.y));
                s2 = __hadd2(s2, __builtin_bit_cast(__half2, q.z));
                s3 = __hadd2(s3, __builtin_bit_cast(__half2, q.w));
            }
            *reinterpret_cast<uint4*>(s_v + (r * 38 + c) * 8) = make_uint4(
                __builtin_bit_cast(u32, s0), __builtin_bit_cast(u32, s1),
                __builtin_bit_cast(u32, s2), __builtin_bit_cast(u32, s3));
        }
    };
    auto horiz = [&](uint4 (&rr)[4]) {
#pragma unroll
        for (int i = 0; i < 4; i++) {              // 32 rows x 32 out-cols
            int u = tid + i * 256;
            int r = u >> 5, cx = u & 31;
            __half2 s0 = __builtin_bit_cast(__half2, 0u);
            __half2 s1 = s0, s2 = s0, s3 = s0;
#pragma unroll
            for (int d = 0; d < 7; d++) {
                uint4 q = *reinterpret_cast<const uint4*>(s_v + (r * 38 + cx + d) * 8);
                s0 = __hadd2(s0, __builtin_bit_cast(__half2, q.x));
                s1 = __hadd2(s1, __builtin_bit_cast(__half2, q.y));
                s2 = __hadd2(s2, __builtin_bit_cast(__half2, q.z));
                s3 = __hadd2(s3, __builtin_bit_cast(__half2, q.w));
            }
            rr[i] = make_uint4(
                __builtin_bit_cast(u32, s0), __builtin_bit_cast(u32, s1),
                __builtin_bit_cast(u32, s2), __builtin_bit_cast(u32, s3));
        }
    };

    uint4 rA[4], rB[4];
#pragma unroll
    for (int i = 0; i < 4; i++) rB[i] = make_uint4(0u, 0u, 0u, 0u);

    stage(oA);
    __syncthreads();
    vert();
    __syncthreads();
    horiz(rA);
    if (hasB) {
        __syncthreads();           // rA-horiz reads done; safe to overwrite s_w
        stage(oA + 1);
        __syncthreads();
        vert();
        __syncthreads();
        horiz(rB);
    }

#pragma unroll
    for (int i = 0; i < 4; i++) {
        int u = tid + i * 256;
        int r = u >> 5, cx = u & 31;
        int y = (h0 + r) * 128 + (w0 + cx);
        u32* dst = WsP + ((size_t)o2 * HW + y) * 8;
        uint4 lo = make_uint4(
            __builtin_amdgcn_perm(rB[i].x, rA[i].x, SELLO),
            __builtin_amdgcn_perm(rB[i].x, rA[i].x, SELHI),
            __builtin_amdgcn_perm(rB[i].y, rA[i].y, SELLO),
            __builtin_amdgcn_perm(rB[i].y, rA[i].y, SELHI));
        uint4 hi = make_uint4(
            __builtin_amdgcn_perm(rB[i].z, rA[i].z, SELLO),
            __builtin_amdgcn_perm(rB[i].z, rA[i].z, SELHI),
            __builtin_amdgcn_perm(rB[i].w, rA[i].w, SELLO),
            0u);
        *reinterpret_cast<uint4*>(dst) = lo;
        *reinterpret_cast<uint4*>(dst + 4) = hi;
    }
}

// ---------------------------------------------------------------------------
// K3 v6: aggregation. v4 geometry (proven 48us) + pair-packed WsP (no perms)
// + ping-pong register prefetch of W(di+1) across the di compute body.
// grid 1024 = 256 tiles (4x16 pix) x 4 c-splits (16ch); 256 thr = 64 pix x 4 cc.
// s_x [16ch][16r][32c] f16; per (di,djp,q): ds_read2 + alignbit + 7 dot2.
// ---------------------------------------------------------------------------
__global__ __launch_bounds__(256, 3) void k_agg(
        const u16* __restrict__ xh, const u32* __restrict__ WsP,
        float* __restrict__ out) {
    __shared__ u16 s_x[16 * 16 * 32];   // [ch][r][c pad32] f16
    int tb = blockIdx.x & 255;
    int csplit = blockIdx.x >> 8;       // 16 channels per split
    int h0 = (tb >> 3) * 4, w0 = (tb & 7) * 16;
    int tid = threadIdx.x;

    for (int it = tid; it < 1024; it += 256) {
        int ch = it >> 6;
        int r = (it >> 2) & 15;
        int c0 = (it & 3) * 8;
        int gy = h0 - 6 + r, gx0 = w0 - 6 + c0;
        int gc = csplit * 16 + ch;
        uint4 v = make_uint4(0u, 0u, 0u, 0u);
        if ((unsigned)gy < 128u) {
            const u16* src = xh + (size_t)gc * HW + gy * 128;
            if (gx0 >= 0 && gx0 <= 120) {
                v = *reinterpret_cast<const uint4*>(src + gx0);
            } else {
                auto pk = [&](int gx) -> u32 {
                    u32 lo = ((unsigned)gx < 128u) ? (u32)src[gx] : 0u;
                    u32 hi = ((unsigned)(gx + 1) < 128u) ? (u32)src[gx + 1] : 0u;
                    return lo | (hi << 16);
                };
                v = make_uint4(pk(gx0), pk(gx0 + 2), pk(gx0 + 4), pk(gx0 + 6));
            }
        }
        *reinterpret_cast<uint4*>(s_x + (ch * 16 + r) * 32 + c0) = v;
    }
    __syncthreads();

    int cc = tid >> 6, pix = tid & 63;
    int pr = pix >> 4, pc = pix & 15;
    int y = (h0 + pr) * 128 + (w0 + pc);
    const u32* wsrc = WsP + (size_t)y * 8;
    const u32* s_x32 = reinterpret_cast<const u32*>(s_x);
    u32 sh = (u32)(pc & 1) * 16;
    int cbase_dw = (pc >> 1);

    float acc[7][4];
#pragma unroll
    for (int k = 0; k < 7; k++)
#pragma unroll
        for (int q = 0; q < 4; q++) acc[k][q] = 0.f;

    auto loadW = [&](int di, uint4 (&A)[7], uint4 (&B)[7]) {
        const u32* wdi = wsrc + (size_t)(di * 7) * (HW * 8);
#pragma unroll
        for (int djp = 0; djp < 7; djp++) {
            const u32* wp = wdi + (size_t)djp * (HW * 8);
            A[djp] = *reinterpret_cast<const uint4*>(wp);
            B[djp] = *reinterpret_cast<const uint4*>(wp + 4);
        }
    };
    auto compute = [&](int di, const uint4 (&A)[7], const uint4 (&B)[7]) {
        int rowb = (pr + di) * 16 + cbase_dw;
#pragma unroll
        for (int djp = 0; djp < 7; djp++) {
#pragma unroll
            for (int q = 0; q < 4; q++) {
                const u32* p = s_x32 + ((cc * 4 + q) * 256 + rowb + djp);
                u32 d0 = p[0], d1 = p[1];
                u32 x2 = __builtin_amdgcn_alignbit(d1, d0, sh);
                dot2acc(acc[0][q], A[djp].x, x2);
                dot2acc(acc[1][q], A[djp].y, x2);
                dot2acc(acc[2][q], A[djp].z, x2);
                dot2acc(acc[3][q], A[djp].w, x2);
                dot2acc(acc[4][q], B[djp].x, x2);
                dot2acc(acc[5][q], B[djp].y, x2);
                dot2acc(acc[6][q], B[djp].z, x2);
            }
        }
    };

    uint4 WA[7], WB[7], WC[7], WD[7];
    loadW(0, WA, WB);
#pragma unroll 1
    for (int di = 0; di < 12; di += 2) {
        loadW(di + 1, WC, WD);     // prefetch next di while computing current
        compute(di, WA, WB);
        loadW(di + 2, WA, WB);     // di+2 <= 12 always inside this loop
        compute(di + 1, WC, WD);
    }
    compute(12, WA, WB);

    int cb = csplit * 16 + cc * 4;
#pragma unroll
    for (int k = 0; k < 7; k++)
#pragma unroll
        for (int q = 0; q < 4; q++)
            out[(k * 64 + cb + q) * HW + y] = acc[k][q];
}

// ---------------------------------------------------------------------------
extern "C" void kernel_launch(void* const* d_in, const int* in_sizes, int n_in,
                              void* d_out, int out_size, void* d_ws, size_t ws_size,
                              hipStream_t stream) {
    (void)in_sizes; (void)n_in; (void)out_size; (void)ws_size;
    const float* x  = (const float*)d_in[0];
    const float* xe = (const float*)d_in[1];
    const float* ye = (const float*)d_in[2];
    const float* lt = (const float*)d_in[3];
    float* out = (float*)d_out;
    char* ws = (char*)d_ws;

    // layout (98.3 MB total):
    u16*   xh     = (u16*)(ws + 0);            //  2,097,152 B (f16 [64][128][128])
    float* xeT    = (float*)(ws + 2097152u);   //  2,097,152
    float* yeT    = (float*)(ws + 4194304u);   //  2,097,152
    u16*   Wkt    = (u16*)(ws + 6291456u);     // 44,302,336 -> 50,593,792
    float* logits = (float*)(ws + 50593792u);  // 11,075,584 (dead after k_softmax)
    u32*   WsP    = (u32*)(ws + 50593792u);    // 47,710,208 -> 98,304,000 (overlays logits)
    // nx/ny/st overlay Wkt head: written by k_prep/k_norms, last read by
    // k_logits; Wkt is written later by k_softmax.
    float*  nx = (float*)(ws + 6291456u);             // 65,536
    float*  ny = (float*)(ws + 6291456u + 65536u);    // 65,536
    float2* st = (float2*)(ws + 6291456u + 131072u);  // 131,072

    k_prep<<<64, 256, 0, stream>>>(x, xe, ye, xh, xeT, yeT, nx, ny);
    k_norms<<<64, 256, 0, stream>>>(ny, lt, st);
    k_logits<<<dim3(13, 64), 1024, 0, stream>>>(xeT, yeT, nx, st, logits);
    k_softmax<<<512, 256, 0, stream>>>(logits, Wkt);
    k_wsum<<<dim3(91, 16), 256, 0, stream>>>(Wkt, WsP);
    k_agg<<<1024, 256, 0, stream>>>(xh, WsP, out);
}

// Round 8
// 155.231 us; speedup vs baseline: 1.3083x; 1.0114x over previous
//
#include <hip/hip_runtime.h>
#include <hip/hip_bf16.h>
#include <hip/hip_fp16.h>

// N3 aggregation: C=64, E=32, H=W=128, K=7, PS=7 (PR=3), WS=13 (WR=6), O=169
#define HW 16384

using u16 = unsigned short;
using u32 = unsigned int;
typedef __attribute__((ext_vector_type(2))) float f32x2;

__device__ __forceinline__ u16 f2h(float f) {
    __half h = __float2half(f);
    return __builtin_bit_cast(u16, h);
}
// acc += a.x*b.x + a.y*b.y  (f16 pairs, f32 accumulate)
__device__ __forceinline__ void dot2acc(float& acc, u32 a, u32 b) {
    asm("v_dot2_f32_f16 %0, %1, %2, %0" : "+v"(acc) : "v"(a), "v"(b));
}
#define SELLO 0x05040100u
#define SELHI 0x07060302u

// ---------------------------------------------------------------------------
// K0: transposes + per-pixel norms. grid 64 x 256. one thread per pixel.
// ---------------------------------------------------------------------------
__global__ __launch_bounds__(256) void k_prep(
        const float* __restrict__ x, const float* __restrict__ xe,
        const float* __restrict__ ye,
        u16* __restrict__ xh, float* __restrict__ xeT,
        float* __restrict__ yeT, float* __restrict__ nx, float* __restrict__ ny) {
    int y = blockIdx.x * 256 + threadIdx.x;

#pragma unroll
    for (int c = 0; c < 64; c++)
        xh[c * HW + y] = f2h(x[c * HW + y]);

    float sx = 0.f, sy = 0.f;
#pragma unroll
    for (int e0 = 0; e0 < 32; e0 += 4) {
        float4 v = make_float4(xe[(e0 + 0) * HW + y], xe[(e0 + 1) * HW + y],
                               xe[(e0 + 2) * HW + y], xe[(e0 + 3) * HW + y]);
        *reinterpret_cast<float4*>(xeT + y * 32 + e0) = v;
        sx += v.x * v.x + v.y * v.y + v.z * v.z + v.w * v.w;
        float4 u = make_float4(ye[(e0 + 0) * HW + y], ye[(e0 + 1) * HW + y],
                               ye[(e0 + 2) * HW + y], ye[(e0 + 3) * HW + y]);
        *reinterpret_cast<float4*>(yeT + y * 32 + e0) = u;
        sy += u.x * u.x + u.y * u.y + u.z * u.z + u.w * u.w;
    }
    nx[y] = sx;
    ny[y] = sy;
}

// ---------------------------------------------------------------------------
// K0b: st[y] = (tinv, tinv*Sy), tinv = exp(-boxsum(lt)/49), Sy = boxsum(ny).
// ---------------------------------------------------------------------------
__global__ __launch_bounds__(256) void k_norms(
        const float* __restrict__ ny, const float* __restrict__ lt,
        float2* __restrict__ st) {
    int y = blockIdx.x * 256 + threadIdx.x;
    int py = y >> 7, px = y & 127;
    float s = 0.f, t = 0.f;
    for (int dy = -3; dy <= 3; dy++)
        for (int dx = -3; dx <= 3; dx++) {
            int yy = py + dy, xx = px + dx;
            if ((unsigned)yy < 128u && (unsigned)xx < 128u) {
                int p = yy * 128 + xx;
                s += ny[p];
                t += lt[p];
            }
        }
    float tinv = __expf(-t * (1.0f / 49.0f));
    st[y] = make_float2(tinv, tinv * s);
}

// ---------------------------------------------------------------------------
// K1 v2: logits[o][y] = -tinv*( Sy(y) + boxsum_z( nx(z+o) - 2*ye(z).xe(z+o) ) ).
// grid (13 di, 64 tiles of 16x16), 1024 threads. (unchanged)
// ---------------------------------------------------------------------------
__global__ __launch_bounds__(1024) void k_logits(
        const float* __restrict__ xeT, const float* __restrict__ yeT,
        const float* __restrict__ nxg, const float2* __restrict__ st,
        float* __restrict__ logits) {
#pragma clang fp contract(fast)
    __shared__ __align__(16) char arena[123904];
    float* s_xe = (float*)arena;              // 748 cells * 32 dw, swizzled
    float* s_nx = (float*)(arena + 95744);    // 748
    float* s_d2 = (float*)(arena + 98736);    // 13 * 484
    float* s_hs = (float*)arena;              // overlay after compute: 13*22*16

    int di = blockIdx.x;
    int tile = blockIdx.y;
    int h0 = (tile >> 3) * 16, w0 = (tile & 7) * 16;
    int gr0 = h0 + di - 9, gc0 = w0 - 9;
    int tid = threadIdx.x;

    for (int idx = tid; idx < 748 * 8; idx += 1024) {
        int cell = idx >> 3, q = idx & 7;
        int r = cell / 34, c = cell - r * 34;
        int gy = gr0 + r, gx = gc0 + c;
        float4 v = make_float4(0.f, 0.f, 0.f, 0.f);
        if ((unsigned)gy < 128u && (unsigned)gx < 128u)
            v = *reinterpret_cast<const float4*>(xeT + (size_t)(gy * 128 + gx) * 32 + q * 4);
        *reinterpret_cast<float4*>(s_xe + cell * 32 + ((q ^ (cell & 7)) << 2)) = v;
    }
    for (int idx = tid; idx < 748; idx += 1024) {
        int r = idx / 34, c = idx - r * 34;
        int gy = gr0 + r, gx = gc0 + c;
        float v = 0.f;
        if ((unsigned)gy < 128u && (unsigned)gx < 128u) v = nxg[gy * 128 + gx];
        s_nx[idx] = v;
    }
    __syncthreads();

    if (tid < 484) {
        int zr = tid / 22, zc = tid - zr * 22;
        int gy = h0 - 3 + zr, gx = w0 - 3 + zc;
        bool zin = ((unsigned)gy < 128u) && ((unsigned)gx < 128u);
        f32x2 yv[16];
#pragma unroll
        for (int j = 0; j < 16; j++) yv[j] = (f32x2){0.f, 0.f};
        if (zin) {
            const float* yp = yeT + (size_t)(gy * 128 + gx) * 32;
#pragma unroll
            for (int j = 0; j < 8; j++) {
                float4 t = *reinterpret_cast<const float4*>(yp + j * 4);
                yv[2 * j] = (f32x2){t.x, t.y};
                yv[2 * j + 1] = (f32x2){t.z, t.w};
            }
        }
        int cell0 = zr * 34 + zc;
#pragma unroll
        for (int dj = 0; dj < 13; dj++) {
            int cell = cell0 + dj;
            const float* bp = s_xe + cell * 32;
            int sw = cell & 7;
            f32x2 a0 = {0.f, 0.f}, a1 = {0.f, 0.f};
#pragma unroll
            for (int q = 0; q < 8; q++) {
                float4 xv = *reinterpret_cast<const float4*>(bp + ((q ^ sw) << 2));
                a0 += ((f32x2){xv.x, xv.y}) * yv[2 * q];
                a1 += ((f32x2){xv.z, xv.w}) * yv[2 * q + 1];
            }
            float cr = a0.x + a0.y + a1.x + a1.y;
            float d2v = fmaf(-2.f, cr, s_nx[cell]);
            s_d2[dj * 484 + tid] = zin ? d2v : 0.f;
        }
    }
    __syncthreads();

    for (int idx = tid; idx < 4576; idx += 1024) {
        int dj = idx / 352, rem = idx - dj * 352;
        int r = rem >> 4, c = rem & 15;
        const float* p = s_d2 + dj * 484 + r * 22 + c;
        float s = p[0] + p[1] + p[2] + p[3] + p[4] + p[5] + p[6];
        s_hs[(dj * 22 + r) * 16 + c] = s;
    }
    __syncthreads();

    for (int idx = tid; idx < 3328; idx += 1024) {
        int dj = idx >> 8, rem = idx & 255;
        int i = rem >> 4, jj = rem & 15;
        const float* p = s_hs + (dj * 22 + i) * 16 + jj;
        float s = p[0] + p[16] + p[32] + p[48] + p[64] + p[80] + p[96];
        int y = (h0 + i) * 128 + (w0 + jj);
        float2 ab = st[y];
        logits[(di * 13 + dj) * HW + y] = -fmaf(ab.x, s, ab.y);
    }
}

// ---------------------------------------------------------------------------
// K2: K=7 rounds of exclusion softmax over O=169. grid 512 x 256. (unchanged)
// ---------------------------------------------------------------------------
__global__ __launch_bounds__(256) void k_softmax(
        const float* __restrict__ logits, u16* __restrict__ Wkt) {
    __shared__ float s_lg[169 * 34];
    int tid = threadIdx.x;
    int y0 = blockIdx.x * 32;
    for (int idx = tid; idx < 169 * 32; idx += 256) {
        int o = idx >> 5, p = idx & 31;
        s_lg[o * 34 + p] = logits[o * HW + y0 + p];
    }
    __syncthreads();
    int pix = tid >> 3, t = tid & 7;
    int y = y0 + pix;
    float l[22];
#pragma unroll
    for (int j = 0; j < 22; j++) {
        int o = t + 8 * j;
        l[j] = (o < 169) ? s_lg[o * 34 + pix] : -3e38f;
    }
    u32 wp0[22], wp1[22], wp2[22], wp3[22];
#pragma unroll
    for (int j = 0; j < 22; j++) { wp0[j] = 0u; wp1[j] = 0u; wp2[j] = 0u; wp3[j] = 0u; }

    float e[22];
#pragma unroll
    for (int k = 0; k < 7; k++) {
        float m = -3e38f;
#pragma unroll
        for (int j = 0; j < 22; j++) m = fmaxf(m, l[j]);
        m = fmaxf(m, __shfl_xor(m, 1));
        m = fmaxf(m, __shfl_xor(m, 2));
        m = fmaxf(m, __shfl_xor(m, 4));
        float s = 0.f;
#pragma unroll
        for (int j = 0; j < 22; j++) { e[j] = __expf(l[j] - m); s += e[j]; }
        s += __shfl_xor(s, 1);
        s += __shfl_xor(s, 2);
        s += __shfl_xor(s, 4);
        float rs = 1.0f / s;
#pragma unroll
        for (int j = 0; j < 22; j++) {
            float w = e[j] * rs;
            u32 h = (u32)f2h(w);
            if (k == 0) wp0[j] |= h;
            else if (k == 1) wp0[j] |= h << 16;
            else if (k == 2) wp1[j] |= h;
            else if (k == 3) wp1[j] |= h << 16;
            else if (k == 4) wp2[j] |= h;
            else if (k == 5) wp2[j] |= h << 16;
            else wp3[j] |= h;
            if (k < 6) l[j] += __logf(fmaxf(1.0f - w, 1e-6f));
        }
    }
#pragma unroll
    for (int j = 0; j < 22; j++) {
        int o = t + 8 * j;
        if (o < 169)
            *reinterpret_cast<uint4*>(Wkt + (o * HW + y) * 8) =
                make_uint4(wp0[j], wp1[j], wp2[j], wp3[j]);
    }
}

// ---------------------------------------------------------------------------
// K2b v2: 7x7 boxsum of Wkt(f16) -> PAIR-PACKED WsP[o2][y][8 u32],
// u32[k] = (f16 w(di,2djp,k) , f16 w(di,2djp+1,k)); slot 7 = 0. (unchanged)
// ---------------------------------------------------------------------------
__global__ __launch_bounds__(256) void k_wsum(
        const u16* __restrict__ Wkt, u32* __restrict__ WsP) {
    __shared__ u16 s_w[38 * 39 * 8];   // [row][col pad39][k8]
    __shared__ u16 s_v[32 * 38 * 8];   // [outrow][col][k8] f16 vertical sums
    int o2 = blockIdx.x;
    int di = o2 / 7, djp = o2 - di * 7;
    int oA = di * 13 + 2 * djp;
    bool hasB = (djp < 6);
    int tile = blockIdx.y;
    int h0 = (tile >> 2) * 32, w0 = (tile & 3) * 32;
    int tid = threadIdx.x;

    auto stage = [&](int o) {
        const u16* src = Wkt + (size_t)o * (HW * 8);
        for (int idx = tid; idx < 38 * 38; idx += 256) {
            int r = idx / 38, c = idx - r * 38;
            int gy = h0 - 3 + r, gx = w0 - 3 + c;
            uint4 v = make_uint4(0u, 0u, 0u, 0u);
            if ((unsigned)gy < 128u && (unsigned)gx < 128u)
                v = *reinterpret_cast<const uint4*>(src + (gy * 128 + gx) * 8);
            *reinterpret_cast<uint4*>(s_w + (r * 39 + c) * 8) = v;
        }
    };
    auto vert = [&]() {
        for (int u = tid; u < 1216; u += 256) {   // 32 out-rows x 38 cols
            int r = u / 38, c = u - r * 38;
            __half2 s0 = __builtin_bit_cast(__half2, 0u);
            __half2 s1 = s0, s2 = s0, s3 = s0;
#pragma unroll
            for (int d = 0; d < 7; d++) {
                uint4 q = *reinterpret_cast<const uint4*>(s_w + ((r + d) * 39 + c) * 8);
                s0 = __hadd2(s0, __builtin_bit_cast(__half2, q.x));
                s1 = __hadd2(s1, __builtin_bit_cast(__half2, q.y));
                s2 = __hadd2(s2, __builtin_bit_cast(__half2, q.z));
                s3 = __hadd2(s3, __builtin_bit_cast(__half2, q.w));
            }
            *reinterpret_cast<uint4*>(s_v + (r * 38 + c) * 8) = make_uint4(
                __builtin_bit_cast(u32, s0), __builtin_bit_cast(u32, s1),
                __builtin_bit_cast(u32, s2), __builtin_bit_cast(u32, s3));
        }
    };
    auto horiz = [&](uint4 (&rr)[4]) {
#pragma unroll
        for (int i = 0; i < 4; i++) {              // 32 rows x 32 out-cols
            int u = tid + i * 256;
            int r = u >> 5, cx = u & 31;
            __half2 s0 = __builtin_bit_cast(__half2, 0u);
            __half2 s1 = s0, s2 = s0, s3 = s0;
#pragma unroll
            for (int d = 0; d < 7; d++) {
                uint4 q = *reinterpret_cast<const uint4*>(s_v + (r * 38 + cx + d) * 8);
                s0 = __hadd2(s0, __builtin_bit_cast(__half2, q.x));
                s1 = __hadd2(s1, __builtin_bit_cast(__half2, q.y));
                s2 = __hadd2(s2, __builtin_bit_cast(__half2, q.z));
                s3 = __hadd2(s3, __builtin_bit_cast(__half2, q.w));
            }
            rr[i] = make_uint4(
                __builtin_bit_cast(u32, s0), __builtin_bit_cast(u32, s1),
                __builtin_bit_cast(u32, s2), __builtin_bit_cast(u32, s3));
        }
    };

    uint4 rA[4], rB[4];
#pragma unroll
    for (int i = 0; i < 4; i++) rB[i] = make_uint4(0u, 0u, 0u, 0u);

    stage(oA);
    __syncthreads();
    vert();
    __syncthreads();
    horiz(rA);
    if (hasB) {
        __syncthreads();           // rA-horiz reads done; safe to overwrite s_w
        stage(oA + 1);
        __syncthreads();
        vert();
        __syncthreads();
        horiz(rB);
    }

#pragma unroll
    for (int i = 0; i < 4; i++) {
        int u = tid + i * 256;
        int r = u >> 5, cx = u & 31;
        int y = (h0 + r) * 128 + (w0 + cx);
        u32* dst = WsP + ((size_t)o2 * HW + y) * 8;
        uint4 lo = make_uint4(
            __builtin_amdgcn_perm(rB[i].x, rA[i].x, SELLO),
            __builtin_amdgcn_perm(rB[i].x, rA[i].x, SELHI),
            __builtin_amdgcn_perm(rB[i].y, rA[i].y, SELLO),
            __builtin_amdgcn_perm(rB[i].y, rA[i].y, SELHI));
        uint4 hi = make_uint4(
            __builtin_amdgcn_perm(rB[i].z, rA[i].z, SELLO),
            __builtin_amdgcn_perm(rB[i].z, rA[i].z, SELHI),
            __builtin_amdgcn_perm(rB[i].w, rA[i].w, SELLO),
            0u);
        *reinterpret_cast<uint4*>(dst) = lo;
        *reinterpret_cast<uint4*>(dst + 4) = hi;
    }
}

// ---------------------------------------------------------------------------
// K3 v7: aggregation, whole-C blocks (no c-split -> W read once per pixel,
// L1-broadcast across the 8 cc waves) + pair-packed WsP + di ping-pong W
// prefetch. grid 256 tiles (4x16 pix); 512 thr = 64 pix x 8 cc (8ch each).
// s_x [64ch][16r][32c] f16 = 64KB. Per (di,ch): row's 8 dwords hoisted via
// 4x ds_read2_b32, then 7 alignbit + 7x7 dot2.
// ---------------------------------------------------------------------------
__global__ __launch_bounds__(512, 2) void k_agg(
        const u16* __restrict__ xh, const u32* __restrict__ WsP,
        float* __restrict__ out) {
    __shared__ u16 s_x[64 * 16 * 32];   // [ch][r][c] f16, 64KB
    int tb = blockIdx.x;
    int h0 = (tb >> 3) * 4, w0 = (tb & 7) * 16;
    int tid = threadIdx.x;

    // stage: 4096 units = 64ch x 16r x 4 chunks of 8 cols
#pragma unroll
    for (int i = 0; i < 8; i++) {
        int it = tid + i * 512;
        int ch = it >> 6;
        int r = (it >> 2) & 15;
        int c0 = (it & 3) * 8;
        int gy = h0 - 6 + r, gx0 = w0 - 6 + c0;
        uint4 v = make_uint4(0u, 0u, 0u, 0u);
        if ((unsigned)gy < 128u) {
            const u16* src = xh + (size_t)ch * HW + gy * 128;
            if (gx0 >= 0 && gx0 <= 120) {
                v = *reinterpret_cast<const uint4*>(src + gx0);
            } else {
                auto pk = [&](int gx) -> u32 {
                    u32 lo = ((unsigned)gx < 128u) ? (u32)src[gx] : 0u;
                    u32 hi = ((unsigned)(gx + 1) < 128u) ? (u32)src[gx + 1] : 0u;
                    return lo | (hi << 16);
                };
                v = make_uint4(pk(gx0), pk(gx0 + 2), pk(gx0 + 4), pk(gx0 + 6));
            }
        }
        *reinterpret_cast<uint4*>(s_x + (ch * 16 + r) * 32 + c0) = v;
    }
    __syncthreads();

    int cc = tid >> 6, pix = tid & 63;
    int pr = pix >> 4, pc = pix & 15;
    int y = (h0 + pr) * 128 + (w0 + pc);
    const u32* wsrc = WsP + (size_t)y * 8;
    const u32* s_x32 = reinterpret_cast<const u32*>(s_x);
    u32 sh = (u32)(pc & 1) * 16;
    int base0 = cc * 8 * 256 + (pc >> 1);   // + q*256 + (pr+di)*16

    float acc[7][8];
#pragma unroll
    for (int k = 0; k < 7; k++)
#pragma unroll
        for (int q = 0; q < 8; q++) acc[k][q] = 0.f;

    auto loadW = [&](int di, uint4 (&A)[7], uint4 (&B)[7]) {
        const u32* wdi = wsrc + (size_t)(di * 7) * (HW * 8);
#pragma unroll
        for (int djp = 0; djp < 7; djp++) {
            const u32* wp = wdi + (size_t)djp * (HW * 8);
            A[djp] = *reinterpret_cast<const uint4*>(wp);
            B[djp] = *reinterpret_cast<const uint4*>(wp + 4);
        }
    };
    auto compute = [&](int di, const uint4 (&A)[7], const uint4 (&B)[7]) {
        int rowoff = (pr + di) * 16;
#pragma unroll
        for (int q = 0; q < 8; q++) {
            const u32* p = s_x32 + base0 + q * 256 + rowoff;
            u32 f0 = p[0], f1 = p[1], f2 = p[2], f3 = p[3];
            u32 f4 = p[4], f5 = p[5], f6 = p[6], f7 = p[7];
            u32 x2;
            x2 = __builtin_amdgcn_alignbit(f1, f0, sh);
            dot2acc(acc[0][q], A[0].x, x2); dot2acc(acc[1][q], A[0].y, x2);
            dot2acc(acc[2][q], A[0].z, x2); dot2acc(acc[3][q], A[0].w, x2);
            dot2acc(acc[4][q], B[0].x, x2); dot2acc(acc[5][q], B[0].y, x2);
            dot2acc(acc[6][q], B[0].z, x2);
            x2 = __builtin_amdgcn_alignbit(f2, f1, sh);
            dot2acc(acc[0][q], A[1].x, x2); dot2acc(acc[1][q], A[1].y, x2);
            dot2acc(acc[2][q], A[1].z, x2); dot2acc(acc[3][q], A[1].w, x2);
            dot2acc(acc[4][q], B[1].x, x2); dot2acc(acc[5][q], B[1].y, x2);
            dot2acc(acc[6][q], B[1].z, x2);
            x2 = __builtin_amdgcn_alignbit(f3, f2, sh);
            dot2acc(acc[0][q], A[2].x, x2); dot2acc(acc[1][q], A[2].y, x2);
            dot2acc(acc[2][q], A[2].z, x2); dot2acc(acc[3][q], A[2].w, x2);
            dot2acc(acc[4][q], B[2].x, x2); dot2acc(acc[5][q], B[2].y, x2);
            dot2acc(acc[6][q], B[2].z, x2);
            x2 = __builtin_amdgcn_alignbit(f4, f3, sh);
            dot2acc(acc[0][q], A[3].x, x2); dot2acc(acc[1][q], A[3].y, x2);
            dot2acc(acc[2][q], A[3].z, x2); dot2acc(acc[3][q], A[3].w, x2);
            dot2acc(acc[4][q], B[3].x, x2); dot2acc(acc[5][q], B[3].y, x2);
            dot2acc(acc[6][q], B[3].z, x2);
            x2 = __builtin_amdgcn_alignbit(f5, f4, sh);
            dot2acc(acc[0][q], A[4].x, x2); dot2acc(acc[1][q], A[4].y, x2);
            dot2acc(acc[2][q], A[4].z, x2); dot2acc(acc[3][q], A[4].w, x2);
            dot2acc(acc[4][q], B[4].x, x2); dot2acc(acc[5][q], B[4].y, x2);
            dot2acc(acc[6][q], B[4].z, x2);
            x2 = __builtin_amdgcn_alignbit(f6, f5, sh);
            dot2acc(acc[0][q], A[5].x, x2); dot2acc(acc[1][q], A[5].y, x2);
            dot2acc(acc[2][q], A[5].z, x2); dot2acc(acc[3][q], A[5].w, x2);
            dot2acc(acc[4][q], B[5].x, x2); dot2acc(acc[5][q], B[5].y, x2);
            dot2acc(acc[6][q], B[5].z, x2);
            x2 = __builtin_amdgcn_alignbit(f7, f6, sh);
            dot2acc(acc[0][q], A[6].x, x2); dot2acc(acc[1][q], A[6].y, x2);
            dot2acc(acc[2][q], A[6].z, x2); dot2acc(acc[3][q], A[6].w, x2);
            dot2acc(acc[4][q], B[6].x, x2); dot2acc(acc[5][q], B[6].y, x2);
            dot2acc(acc[6][q], B[6].z, x2);
        }
    };

    uint4 WA[7], WB[7], WC[7], WD[7];
    loadW(0, WA, WB);
#pragma unroll 1
    for (int di = 0; di < 12; di += 2) {
        loadW(di + 1, WC, WD);     // prefetch next di while computing current
        compute(di, WA, WB);
        loadW(di + 2, WA, WB);     // di+2 <= 12 always inside this loop
        compute(di + 1, WC, WD);
    }
    compute(12, WA, WB);

#pragma unroll
    for (int k = 0; k < 7; k++)
#pragma unroll
        for (int q = 0; q < 8; q++)
            out[(k * 64 + cc * 8 + q) * HW + y] = acc[k][q];
}

// ---------------------------------------------------------------------------
extern "C" void kernel_launch(void* const* d_in, const int* in_sizes, int n_in,
                              void* d_out, int out_size, void* d_ws, size_t ws_size,
                              hipStream_t stream) {
    (void)in_sizes; (void)n_in; (void)out_size; (void)ws_size;
    const float* x  = (const float*)d_in[0];
    const float* xe = (const float*)d_in[1];
    const float* ye = (const float*)d_in[2];
    const float* lt = (const float*)d_in[3];
    float* out = (float*)d_out;
    char* ws = (char*)d_ws;

    // layout (98.3 MB total):
    u16*   xh     = (u16*)(ws + 0);            //  2,097,152 B (f16 [64][128][128])
    float* xeT    = (float*)(ws + 2097152u);   //  2,097,152
    float* yeT    = (float*)(ws + 4194304u);   //  2,097,152
    u16*   Wkt    = (u16*)(ws + 6291456u);     // 44,302,336 -> 50,593,792
    float* logits = (float*)(ws + 50593792u);  // 11,075,584 (dead after k_softmax)
    u32*   WsP    = (u32*)(ws + 50593792u);    // 47,710,208 -> 98,304,000 (overlays logits)
    // nx/ny/st overlay Wkt head: written by k_prep/k_norms, last read by
    // k_logits; Wkt is written later by k_softmax.
    float*  nx = (float*)(ws + 6291456u);             // 65,536
    float*  ny = (float*)(ws + 6291456u + 65536u);    // 65,536
    float2* st = (float2*)(ws + 6291456u + 131072u);  // 131,072

    k_prep<<<64, 256, 0, stream>>>(x, xe, ye, xh, xeT, yeT, nx, ny);
    k_norms<<<64, 256, 0, stream>>>(ny, lt, st);
    k_logits<<<dim3(13, 64), 1024, 0, stream>>>(xeT, yeT, nx, st, logits);
    k_softmax<<<512, 256, 0, stream>>>(logits, Wkt);
    k_wsum<<<dim3(91, 16), 256, 0, stream>>>(Wkt, WsP);
    k_agg<<<256, 512, 0, stream>>>(xh, WsP, out);
}